// Round 5
// baseline (334.337 us; speedup 1.0000x reference)
//
#include <hip/hip_runtime.h>
#include <cstdint>

// Problem constants (reference: B,J,D,W,H,EH,L = 128,8192,32,4,128,256,32)
#define BDIM 128
#define JDIM 8192

typedef short s8x __attribute__((ext_vector_type(8)));   // 8 bf16 in 4 VGPRs (MFMA A/B frag)
typedef float f4x __attribute__((ext_vector_type(4)));   // MFMA C/D frag

// f32 -> bf16 via scalar casts: compiler fuses pairs into v_cvt_pk_bf16_f32
// (learn_hip m240: scalar casts beat hand-written cvt_pk asm). RNE semantics.
__device__ __forceinline__ unsigned short bf16u(float f) {
    return __builtin_bit_cast(unsigned short, (__bf16)f);
}
__device__ __forceinline__ unsigned int pkbf(float lo, float hi) {
    return (unsigned int)bf16u(lo) | ((unsigned int)bf16u(hi) << 16);
}
__device__ __forceinline__ float bf2f(unsigned int s) {
    return __uint_as_float(s << 16);
}

// 16-lane (DPP-row) all-reduce sum: xor1, xor2, ^7, ^15 — pure VALU, no DS pipe.
template <int CTRL>
__device__ __forceinline__ float dppadd(float x) {
    int y = __builtin_amdgcn_update_dpp(0, __builtin_bit_cast(int, x), CTRL, 0xF, 0xF, true);
    return x + __builtin_bit_cast(float, y);
}
__device__ __forceinline__ float allred16(float x) {
    x = dppadd<0xB1>(x);    // quad_perm [1,0,3,2]  : lane ^ 1
    x = dppadd<0x4E>(x);    // quad_perm [2,3,0,1]  : lane ^ 2
    x = dppadd<0x141>(x);   // row_half_mirror      : lane ^ 7
    x = dppadd<0x140>(x);   // row_mirror           : lane ^ 15
    return x;
}

// ---------------------------------------------------------------------------
// Kernel 0: feW[j][h] = fe[j,:] @ h_w1[1:,:] + h_b1  (stored bf16), plus per-j
// moments for closed-form LN1 stats; block j==0 writes mean(w0), mean(w0^2).
// ---------------------------------------------------------------------------
__global__ __launch_bounds__(128) void k_prep(
    const float* __restrict__ fe, const float* __restrict__ hw1,
    const float* __restrict__ hb1,
    unsigned short* __restrict__ feWb, float* __restrict__ aux,
    float* __restrict__ scal)
{
    const int j = blockIdx.x, h = threadIdx.x;
    float acc = hb1[h];
#pragma unroll
    for (int d = 0; d < 32; ++d)
        acc = fmaf(fe[j * 32 + d], hw1[(1 + d) * 128 + h], acc);
    feWb[(size_t)j * 128 + h] = bf16u(acc);

    const float w0h = hw1[h];
    float s1 = acc, sx = w0h * acc, s2 = acc * acc;
#pragma unroll
    for (int m = 1; m <= 32; m <<= 1) {
        s1 += __shfl_xor(s1, m); sx += __shfl_xor(sx, m); s2 += __shfl_xor(s2, m);
    }
    __shared__ float red[2][3];
    const int wv = threadIdx.x >> 6, ln = threadIdx.x & 63;
    if (ln == 0) { red[wv][0] = s1; red[wv][1] = sx; red[wv][2] = s2; }
    __syncthreads();
    if (threadIdx.x == 0) {
        aux[j * 4 + 0] = (red[0][0] + red[1][0]) * (1.f / 128.f);
        aux[j * 4 + 1] = (red[0][1] + red[1][1]) * (1.f / 128.f);
        aux[j * 4 + 2] = (red[0][2] + red[1][2]) * (1.f / 128.f);
    }
    if (j == 0) {
        float a = w0h, b = w0h * w0h;
#pragma unroll
        for (int m = 1; m <= 32; m <<= 1) { a += __shfl_xor(a, m); b += __shfl_xor(b, m); }
        __syncthreads();
        if (ln == 0) { red[wv][0] = a; red[wv][1] = b; }
        __syncthreads();
        if (threadIdx.x == 0) {
            scal[0] = (red[0][0] + red[1][0]) * (1.f / 128.f);
            scal[1] = (red[0][1] + red[1][1]) * (1.f / 128.f);
        }
    }
}

// ---------------------------------------------------------------------------
// Kernel 1: per cell (b,j): pre -> LN1 -> relu -> (MFMA) @h_w2 -> +b2 -> LN2
// -> relu -> gates (MFMA + DPP all-reduce) -> exp(logit-10) -> weighted
// accumulation of head_sums in registers.  Wave = 1 j x 16 b.
// grid = (njb j-blocks, 8 b-tiles), block = 4 waves, jpw j's per wave.
// NOTE: (256,2): at (256,4) the 64-VGPR cap spills wf/hsacc to scratch
// (R3: FETCH 5.4MB->343MB). At (256,2) kernel uses 88 VGPR -> 5 blocks/CU
// possible; grid sized 2048 blocks (NJB=256) to fill that.
// ---------------------------------------------------------------------------
__global__ __launch_bounds__(256, 2) void k_main(
    const float* __restrict__ x, const int* __restrict__ mask,
    const unsigned short* __restrict__ feWb, const float* __restrict__ aux,
    const float* __restrict__ scal,
    const float* __restrict__ hw1, const float* __restrict__ ln1w,
    const float* __restrict__ ln1b,
    const float* __restrict__ hw2, const float* __restrict__ hb2,
    const float* __restrict__ ln2w, const float* __restrict__ ln2b,
    const float* __restrict__ gw1, const float* __restrict__ gb1,
    const float* __restrict__ gw2, const float* __restrict__ gb2,
    float* __restrict__ P, float* __restrict__ SEb, int njb, int jpw)
{
    __shared__ float w0s[128], g1s[128], b1s[128];
    __shared__ float holds[8][576];   // [wave*2+parity][16 rows x pitch 36]
    __shared__ float hsL[2048];
    __shared__ float seL[64];

    const int tid = threadIdx.x, l = tid & 63;
    const int wv = __builtin_amdgcn_readfirstlane(tid >> 6);
    const int c = l & 15, g = l >> 4;
    const int bt = blockIdx.y, bx = blockIdx.x;
    const int b0 = bt * 16;

    if (tid < 128) { w0s[tid] = hw1[tid]; g1s[tid] = ln1w[tid]; b1s[tid] = ln1b[tid]; }
    // zero the block-combine buffers (atomicAdd combine at the end)
    for (int i = tid; i < 2048; i += 256) hsL[i] = 0.f;
    if (tid < 64) seL[tid] = 0.f;
    __syncthreads();

    const float mw0 = scal[0], q0 = scal[1];

    // B-fragments of h_w2 (K=128 -> 4 k-tiles; N=32 -> 2 n-tiles).
    s8x wf[2][4];
#pragma unroll
    for (int nt = 0; nt < 2; ++nt)
#pragma unroll
        for (int t = 0; t < 4; ++t) {
            const int kb = 32 * t + 8 * g, n = 16 * nt + c;
            uint4 u;
            u.x = pkbf(hw2[(kb + 0) * 32 + n], hw2[(kb + 1) * 32 + n]);
            u.y = pkbf(hw2[(kb + 2) * 32 + n], hw2[(kb + 3) * 32 + n]);
            u.z = pkbf(hw2[(kb + 4) * 32 + n], hw2[(kb + 5) * 32 + n]);
            u.w = pkbf(hw2[(kb + 6) * 32 + n], hw2[(kb + 7) * 32 + n]);
            wf[nt][t] = __builtin_bit_cast(s8x, u);
        }
    // B-fragment of g_w1 (32x16): k = 8g+i, col m = c.
    s8x g1f;
    {
        uint4 u;
        u.x = pkbf(gw1[(8 * g + 0) * 16 + c], gw1[(8 * g + 1) * 16 + c]);
        u.y = pkbf(gw1[(8 * g + 2) * 16 + c], gw1[(8 * g + 3) * 16 + c]);
        u.z = pkbf(gw1[(8 * g + 4) * 16 + c], gw1[(8 * g + 5) * 16 + c]);
        u.w = pkbf(gw1[(8 * g + 6) * 16 + c], gw1[(8 * g + 7) * 16 + c]);
        g1f = __builtin_bit_cast(s8x, u);
    }
    const float hb2a = hb2[c],      hb2b = hb2[16 + c];
    const float g2a  = ln2w[c],     g2b  = ln2w[16 + c];
    const float z2a  = ln2b[c],     z2b  = ln2b[16 + c];
    const float gb1c = gb1[c];
    float gw2c[4], gb2v[4];
#pragma unroll
    for (int w = 0; w < 4; ++w) { gw2c[w] = gw2[c * 4 + w]; gb2v[w] = gb2[w]; }

    const int j0 = (bx * 4 + wv) * jpw;
    const float* xrow = x + (size_t)(b0 + c) * JDIM;
    const int*   mrow = mask + (size_t)(b0 + c) * JDIM;

    float hsacc[4][4][2];
    float seacc[4][4];
#pragma unroll
    for (int r = 0; r < 4; ++r)
#pragma unroll
        for (int w = 0; w < 4; ++w) {
            hsacc[r][w][0] = 0.f; hsacc[r][w][1] = 0.f; seacc[r][w] = 0.f;
        }

    for (int jj = 0; jj < jpw; ++jj) {
        const int j = j0 + jj;
        const float xv = xrow[j];
        const int   mv = mrow[j];
        const float4 au = *(const float4*)(aux + j * 4);
        const float m1 = au.x, qx = au.y, q2 = au.z;
        const float mu = fmaf(xv, mw0, m1);
        const float e2 = fmaf(xv * xv, q0, fmaf(2.f * xv, qx, q2));
        const float rs = rsqrtf(e2 - mu * mu + 1e-5f);
        const float nms = -mu * rs;

        f4x ca = {0.f, 0.f, 0.f, 0.f}, cbv = {0.f, 0.f, 0.f, 0.f};
        const unsigned short* fj = feWb + (size_t)j * 128;
#pragma unroll
        for (int t = 0; t < 4; ++t) {
            const int kb = 32 * t + 8 * g;
            const uint4 fw = *(const uint4*)(fj + kb);
            const float pf0 = bf2f(fw.x & 0xffffu), pf1 = bf2f(fw.x >> 16);
            const float pf2 = bf2f(fw.y & 0xffffu), pf3 = bf2f(fw.y >> 16);
            const float pf4 = bf2f(fw.z & 0xffffu), pf5 = bf2f(fw.z >> 16);
            const float pf6 = bf2f(fw.w & 0xffffu), pf7 = bf2f(fw.w >> 16);
            const float4 wa = *(const float4*)&w0s[kb];
            const float4 wb = *(const float4*)&w0s[kb + 4];
            const float4 ga = *(const float4*)&g1s[kb];
            const float4 gbq = *(const float4*)&g1s[kb + 4];
            const float4 ba = *(const float4*)&b1s[kb];
            const float4 bb = *(const float4*)&b1s[kb + 4];
            const float h0 = fmaxf(fmaf(fmaf(fmaf(xv, wa.x, pf0), rs, nms), ga.x,  ba.x), 0.f);
            const float h1 = fmaxf(fmaf(fmaf(fmaf(xv, wa.y, pf1), rs, nms), ga.y,  ba.y), 0.f);
            const float h2 = fmaxf(fmaf(fmaf(fmaf(xv, wa.z, pf2), rs, nms), ga.z,  ba.z), 0.f);
            const float h3 = fmaxf(fmaf(fmaf(fmaf(xv, wa.w, pf3), rs, nms), ga.w,  ba.w), 0.f);
            const float h4 = fmaxf(fmaf(fmaf(fmaf(xv, wb.x, pf4), rs, nms), gbq.x, bb.x), 0.f);
            const float h5 = fmaxf(fmaf(fmaf(fmaf(xv, wb.y, pf5), rs, nms), gbq.y, bb.y), 0.f);
            const float h6 = fmaxf(fmaf(fmaf(fmaf(xv, wb.z, pf6), rs, nms), gbq.z, bb.z), 0.f);
            const float h7 = fmaxf(fmaf(fmaf(fmaf(xv, wb.w, pf7), rs, nms), gbq.w, bb.w), 0.f);
            uint4 u;
            u.x = pkbf(h0, h1); u.y = pkbf(h2, h3); u.z = pkbf(h4, h5); u.w = pkbf(h6, h7);
            const s8x af = __builtin_bit_cast(s8x, u);
            ca  = __builtin_amdgcn_mfma_f32_16x16x32_bf16(af, wf[0][t], ca,  0, 0, 0);
            cbv = __builtin_amdgcn_mfma_f32_16x16x32_bf16(af, wf[1][t], cbv, 0, 0, 0);
        }

        // + h_b2, LN over D=32 (row = cell 4g+r across the 16-lane c-group)
        float v0[4], v1[4], sr[4], qr[4];
#pragma unroll
        for (int r = 0; r < 4; ++r) {
            v0[r] = ca[r] + hb2a;
            v1[r] = cbv[r] + hb2b;
            sr[r] = v0[r] + v1[r];
            qr[r] = v0[r] * v0[r] + v1[r] * v1[r];
        }
#pragma unroll
        for (int r = 0; r < 4; ++r) { sr[r] = allred16(sr[r]); qr[r] = allred16(qr[r]); }
        float ho0[4], ho1[4];
#pragma unroll
        for (int r = 0; r < 4; ++r) {
            const float m2  = sr[r] * 0.03125f;
            const float rs2 = rsqrtf(fmaf(qr[r], 0.03125f, -m2 * m2) + 1e-5f);
            const float nm2 = -m2 * rs2;
            ho0[r] = fmaxf(fmaf(fmaf(v0[r], rs2, nm2), g2a, z2a), 0.f);
            ho1[r] = fmaxf(fmaf(fmaf(v1[r], rs2, nm2), g2b, z2b), 0.f);
        }

        // stage h_out into per-wave LDS (ping-pong), transpose-read A-frag
        float* hp = &holds[wv * 2 + (jj & 1)][0];
#pragma unroll
        for (int r = 0; r < 4; ++r) {
            hp[(4 * g + r) * 36 + c]      = ho0[r];
            hp[(4 * g + r) * 36 + 16 + c] = ho1[r];
        }
        asm volatile("s_waitcnt lgkmcnt(0)" ::: "memory");
        const float4 ra  = *(const float4*)&hp[c * 36 + 8 * g];
        const float4 rb2 = *(const float4*)&hp[c * 36 + 8 * g + 4];
        uint4 ua;
        ua.x = pkbf(ra.x, ra.y);  ua.y = pkbf(ra.z, ra.w);
        ua.z = pkbf(rb2.x, rb2.y); ua.w = pkbf(rb2.z, rb2.w);
        const s8x af2 = __builtin_bit_cast(s8x, ua);
        f4x gc = {0.f, 0.f, 0.f, 0.f};
        gc = __builtin_amdgcn_mfma_f32_16x16x32_bf16(af2, g1f, gc, 0, 0, 0);

        // gate2 partials + DPP all-reduce over the 16 m-lanes
        float pw[16];
#pragma unroll
        for (int r = 0; r < 4; ++r) {
            const float g1r = fmaxf(gc[r] + gb1c, 0.f);
#pragma unroll
            for (int w = 0; w < 4; ++w) pw[r * 4 + w] = g1r * gw2c[w];
        }
#pragma unroll
        for (int i = 0; i < 16; ++i) pw[i] = allred16(pw[i]);

        // mask bits via ballot (lanes 0..15 hold cells 0..15)
        const unsigned bm = (unsigned)__ballot(mv > 0);
        float fm[4];
#pragma unroll
        for (int r = 0; r < 4; ++r) fm[r] = (float)((bm >> (4 * g + r)) & 1u);

#pragma unroll
        for (int r = 0; r < 4; ++r)
#pragma unroll
            for (int w = 0; w < 4; ++w) {
                const float lg = __builtin_amdgcn_fmed3f(pw[r * 4 + w] + gb2v[w], -10.f, 10.f);
                const float e  = fm[r] * __builtin_amdgcn_exp2f(
                                     fmaf(lg, 1.44269504089f, -14.4269504089f));
                seacc[r][w] += e;
                hsacc[r][w][0] = fmaf(e, ho0[r], hsacc[r][w][0]);
                hsacc[r][w][1] = fmaf(e, ho1[r], hsacc[r][w][1]);
            }
    }

    // combine the 4 waves' partials via LDS atomics (ds_add_f32, no ladder)
    __syncthreads();   // hsL/seL zeroed in prologue; all waves past j-loop
#pragma unroll
    for (int r = 0; r < 4; ++r)
#pragma unroll
        for (int w = 0; w < 4; ++w) {
#pragma unroll
            for (int nt = 0; nt < 2; ++nt) {
                const int idx = ((4 * g + r) * 4 + w) * 32 + c + 16 * nt;
                atomicAdd(&hsL[idx], hsacc[r][w][nt]);
            }
            if (c == 0) atomicAdd(&seL[(4 * g + r) * 4 + w], seacc[r][w]);
        }
    __syncthreads();
    const size_t base = ((size_t)bt * njb + bx) * 2048;
    for (int i = tid; i < 2048; i += 256) P[base + i] = hsL[i];
    if (tid < 64) SEb[((size_t)bt * njb + bx) * 64 + tid] = seL[tid];
}

// ---------------------------------------------------------------------------
// Kernel 2: per b: reduce the njb j-block partials, head_sums = hs/sumexp,
// comb = relu(LN(hs @ c_w + c_b)) (zeroed if no unmasked j), then the two
// e-layers with LN + relu, split into mu / logvar.
// ---------------------------------------------------------------------------
__global__ __launch_bounds__(128) void k_tail(
    const float* __restrict__ P, const float* __restrict__ SEb,
    const float* __restrict__ cw, const float* __restrict__ cbv,
    const float* __restrict__ clnw, const float* __restrict__ clnb,
    const float* __restrict__ ew1, const float* __restrict__ eb1,
    const float* __restrict__ l1w, const float* __restrict__ l1b,
    const float* __restrict__ ew2, const float* __restrict__ eb2,
    const float* __restrict__ l2w, const float* __restrict__ l2b,
    float* __restrict__ out, int njb)
{
    const int b = blockIdx.x, t = threadIdx.x;
    const int bt = b >> 4, bi = b & 15;
    __shared__ float hsLs[128], combL[32], hL[256], seW[4], sred[64], red[4];

    const float* Pb = P + (size_t)bt * njb * 2048 + bi * 128;
    float sacc = 0.f;
#pragma unroll 8
    for (int jc = 0; jc < njb; ++jc) sacc += Pb[(size_t)jc * 2048 + t];

    if (t < 64) {
        const int w = t & 3, part = t >> 2;
        float sp = 0.f;
        for (int q = part; q < njb; q += 16)
            sp += SEb[((size_t)bt * njb + q) * 64 + bi * 4 + w];
        sred[t] = sp;
    }
    __syncthreads();
    if (t < 4) {
        float v = 0.f;
#pragma unroll
        for (int sl = 0; sl < 16; ++sl) v += sred[sl * 4 + t];
        seW[t] = v;
    }
    __syncthreads();
    const bool has = seW[0] > 0.f;
    hsLs[t] = has ? sacc / seW[t >> 5] : 0.f;
    __syncthreads();

    if (t < 32) {
        float cv = cbv[t];
#pragma unroll 4
        for (int f = 0; f < 128; ++f) cv = fmaf(hsLs[f], cw[f * 32 + t], cv);
        float s = cv, q = cv * cv;
#pragma unroll
        for (int m = 1; m <= 16; m <<= 1) { s += __shfl_xor(s, m); q += __shfl_xor(q, m); }
        const float mu = s * (1.f / 32.f);
        const float rsg = rsqrtf(fmaf(q, 1.f / 32.f, -mu * mu) + 1e-5f);
        const float v = fmaf(fmaf(cv, rsg, -mu * rsg), clnw[t], clnb[t]);
        combL[t] = has ? fmaxf(v, 0.f) : 0.f;
    }
    __syncthreads();

    float h0 = eb1[t], h1v = eb1[t + 128];
#pragma unroll 4
    for (int d = 0; d < 32; ++d) {
        const float cd = combL[d];
        h0  = fmaf(cd, ew1[d * 256 + t], h0);
        h1v = fmaf(cd, ew1[d * 256 + t + 128], h1v);
    }
    {
        float s = h0 + h1v, q = h0 * h0 + h1v * h1v;
#pragma unroll
        for (int m = 1; m <= 32; m <<= 1) { s += __shfl_xor(s, m); q += __shfl_xor(q, m); }
        const int wv = t >> 6, ln = t & 63;
        if (ln == 0) { red[wv * 2] = s; red[wv * 2 + 1] = q; }
    }
    __syncthreads();
    {
        const float S = red[0] + red[2], Q = red[1] + red[3];
        const float mu1 = S * (1.f / 256.f);
        const float rs1 = rsqrtf(fmaf(Q, 1.f / 256.f, -mu1 * mu1) + 1e-5f);
        hL[t]       = fmaxf(fmaf(fmaf(h0,  rs1, -mu1 * rs1), l1w[t],       l1b[t]),       0.f);
        hL[t + 128] = fmaxf(fmaf(fmaf(h1v, rs1, -mu1 * rs1), l1w[t + 128], l1b[t + 128]), 0.f);
    }
    __syncthreads();

    if (t < 64) {
        float ov = eb2[t];
#pragma unroll 4
        for (int m = 0; m < 256; ++m) ov = fmaf(hL[m], ew2[m * 64 + t], ov);
        float s = ov, q = ov * ov;
#pragma unroll
        for (int m = 1; m <= 32; m <<= 1) { s += __shfl_xor(s, m); q += __shfl_xor(q, m); }
        const float mu2 = s * (1.f / 64.f);
        const float rs2 = rsqrtf(fmaf(q, 1.f / 64.f, -mu2 * mu2) + 1e-5f);
        const float o = fmaxf(fmaf(fmaf(ov, rs2, -mu2 * rs2), l2w[t], l2b[t]), 0.f);
        if (t < 32) out[b * 32 + t] = o;
        else        out[4096 + b * 32 + (t - 32)] = o;
    }
}

// ---------------------------------------------------------------------------
extern "C" void kernel_launch(void* const* d_in, const int* in_sizes, int n_in,
                              void* d_out, int out_size, void* d_ws, size_t ws_size,
                              hipStream_t stream)
{
    (void)in_sizes; (void)n_in; (void)out_size;
    const float* x    = (const float*)d_in[0];
    const int*   mask = (const int*)d_in[1];
    const float* fe   = (const float*)d_in[2];
    const float* hw1  = (const float*)d_in[3];
    const float* hb1  = (const float*)d_in[4];
    const float* ln1w = (const float*)d_in[5];
    const float* ln1b = (const float*)d_in[6];
    const float* hw2  = (const float*)d_in[7];
    const float* hb2  = (const float*)d_in[8];
    const float* ln2w = (const float*)d_in[9];
    const float* ln2b = (const float*)d_in[10];
    const float* gw1  = (const float*)d_in[11];
    const float* gb1  = (const float*)d_in[12];
    const float* gw2  = (const float*)d_in[13];
    const float* gb2  = (const float*)d_in[14];
    const float* cw   = (const float*)d_in[15];
    const float* cbv  = (const float*)d_in[16];
    const float* clnw = (const float*)d_in[17];
    const float* clnb = (const float*)d_in[18];
    const float* ew1  = (const float*)d_in[19];
    const float* eb1  = (const float*)d_in[20];
    const float* l1w  = (const float*)d_in[21];
    const float* l1b  = (const float*)d_in[22];
    const float* ew2  = (const float*)d_in[23];
    const float* eb2  = (const float*)d_in[24];
    const float* l2w  = (const float*)d_in[25];
    const float* l2b  = (const float*)d_in[26];

    const size_t base = (2u << 20) + (128u << 10) + 256u;
    // choose j-split by available workspace: NJB=256 -> 2048 blocks -> 5
    // resident blocks/CU (88 VGPR, 28KB LDS). Falls back if ws is tight.
    int NJB = 256;
    while (NJB > 64) {
        const size_t need = base + (size_t)8 * NJB * 2048 * 4 + (size_t)8 * NJB * 64 * 4;
        if (ws_size >= need) break;
        NJB >>= 1;
    }
    const int JPW = JDIM / (NJB * 4);

    char* ws = (char*)d_ws;
    unsigned short* feWb = (unsigned short*)ws;                       // 2 MB
    float* aux  = (float*)(ws + (2u << 20));                          // 128 KB
    float* scal = (float*)(ws + (2u << 20) + (128u << 10));           // 256 B
    float* P    = (float*)(ws + base);                                // 8*NJB*2048*4 B
    float* SEb  = (float*)(ws + base + (size_t)8 * NJB * 2048 * 4);   // 8*NJB*64*4 B

    hipLaunchKernelGGL(k_prep, dim3(JDIM), dim3(128), 0, stream,
                       fe, hw1, hb1, feWb, aux, scal);
    hipLaunchKernelGGL(k_main, dim3(NJB, 8), dim3(256), 0, stream,
                       x, mask, feWb, aux, scal,
                       hw1, ln1w, ln1b, hw2, hb2, ln2w, ln2b,
                       gw1, gb1, gw2, gb2, P, SEb, NJB, JPW);
    hipLaunchKernelGGL(k_tail, dim3(BDIM), dim3(128), 0, stream,
                       P, SEb, cw, cbv, clnw, clnb,
                       ew1, eb1, l1w, l1b, ew2, eb2, l2w, l2b,
                       (float*)d_out, NJB);
}

// Round 6
// 247.353 us; speedup vs baseline: 1.3517x; 1.3517x over previous
//
#include <hip/hip_runtime.h>
#include <cstdint>

// Problem constants (reference: B,J,D,W,H,EH,L = 128,8192,32,4,128,256,32)
#define BDIM 128
#define JDIM 8192

typedef short s8x __attribute__((ext_vector_type(8)));   // 8 bf16 in 4 VGPRs (MFMA A/B frag)
typedef float f4x __attribute__((ext_vector_type(4)));   // MFMA C/D frag
typedef float f2x __attribute__((ext_vector_type(2)));   // packed-f32 (v_pk_*_f32)

// f32 -> bf16 via scalar casts: compiler fuses pairs into v_cvt_pk_bf16_f32.
__device__ __forceinline__ unsigned short bf16u(float f) {
    return __builtin_bit_cast(unsigned short, (__bf16)f);
}
__device__ __forceinline__ unsigned int pkbf(float lo, float hi) {
    return (unsigned int)bf16u(lo) | ((unsigned int)bf16u(hi) << 16);
}
// unpack a bf16 pair (lo,hi) -> f2x
__device__ __forceinline__ f2x upk(unsigned int w) {
    f2x r;
    r.x = __uint_as_float(w << 16);
    r.y = __uint_as_float(w & 0xffff0000u);
    return r;
}
__device__ __forceinline__ f2x pkfma(f2x a, f2x b, f2x c) {
#if __has_builtin(__builtin_elementwise_fma)
    return __builtin_elementwise_fma(a, b, c);
#else
    f2x r; r.x = fmaf(a.x, b.x, c.x); r.y = fmaf(a.y, b.y, c.y); return r;
#endif
}
__device__ __forceinline__ f2x pkmax0(f2x a) {
#if __has_builtin(__builtin_elementwise_max)
    f2x z = {0.f, 0.f};
    return __builtin_elementwise_max(a, z);
#else
    f2x r; r.x = fmaxf(a.x, 0.f); r.y = fmaxf(a.y, 0.f); return r;
#endif
}

// 16-lane (DPP-row) all-reduce sum: xor1, xor2, ^7, ^15 — pure VALU, no DS pipe.
template <int CTRL>
__device__ __forceinline__ float dppadd(float x) {
    int y = __builtin_amdgcn_update_dpp(0, __builtin_bit_cast(int, x), CTRL, 0xF, 0xF, true);
    return x + __builtin_bit_cast(float, y);
}
__device__ __forceinline__ float allred16(float x) {
    x = dppadd<0xB1>(x);    // quad_perm [1,0,3,2]  : lane ^ 1
    x = dppadd<0x4E>(x);    // quad_perm [2,3,0,1]  : lane ^ 2
    x = dppadd<0x141>(x);   // row_half_mirror      : lane ^ 7
    x = dppadd<0x140>(x);   // row_mirror           : lane ^ 15
    return x;
}

// ---------------------------------------------------------------------------
// Kernel 0: feW[j][h] = fe[j,:] @ h_w1[1:,:] + h_b1  (stored bf16), plus per-j
// moments for closed-form LN1 stats; block j==0 also writes mean(w0),
// mean(w0^2) and the pre-packed per-lane MFMA B-fragments of h_w2 / g_w1.
// ---------------------------------------------------------------------------
__global__ __launch_bounds__(128) void k_prep(
    const float* __restrict__ fe, const float* __restrict__ hw1,
    const float* __restrict__ hb1,
    const float* __restrict__ hw2, const float* __restrict__ gw1,
    unsigned short* __restrict__ feWb, float* __restrict__ aux,
    float* __restrict__ scal, uint4* __restrict__ fragW)
{
    const int j = blockIdx.x, h = threadIdx.x;
    float acc = hb1[h];
#pragma unroll
    for (int d = 0; d < 32; ++d)
        acc = fmaf(fe[j * 32 + d], hw1[(1 + d) * 128 + h], acc);
    feWb[(size_t)j * 128 + h] = bf16u(acc);

    const float w0h = hw1[h];
    float s1 = acc, sx = w0h * acc, s2 = acc * acc;
#pragma unroll
    for (int m = 1; m <= 32; m <<= 1) {
        s1 += __shfl_xor(s1, m); sx += __shfl_xor(sx, m); s2 += __shfl_xor(s2, m);
    }
    __shared__ float red[2][3];
    const int wv = threadIdx.x >> 6, ln = threadIdx.x & 63;
    if (ln == 0) { red[wv][0] = s1; red[wv][1] = sx; red[wv][2] = s2; }
    __syncthreads();
    if (threadIdx.x == 0) {
        aux[j * 4 + 0] = (red[0][0] + red[1][0]) * (1.f / 128.f);
        aux[j * 4 + 1] = (red[0][1] + red[1][1]) * (1.f / 128.f);
        aux[j * 4 + 2] = (red[0][2] + red[1][2]) * (1.f / 128.f);
    }
    if (j == 0) {
        float a = w0h, b = w0h * w0h;
#pragma unroll
        for (int m = 1; m <= 32; m <<= 1) { a += __shfl_xor(a, m); b += __shfl_xor(b, m); }
        __syncthreads();
        if (ln == 0) { red[wv][0] = a; red[wv][1] = b; }
        __syncthreads();
        if (threadIdx.x == 0) {
            scal[0] = (red[0][0] + red[1][0]) * (1.f / 128.f);
            scal[1] = (red[0][1] + red[1][1]) * (1.f / 128.f);
        }
        // pre-pack per-lane MFMA fragments: layout [frag][lane] for coalesced
        // loads in k_main. frag 0..7 = h_w2 (nt*4+t); frag 8 = g_w1.
        if (threadIdx.x < 64) {
            const int cc = threadIdx.x & 15, gg = threadIdx.x >> 4;
#pragma unroll
            for (int nt = 0; nt < 2; ++nt)
#pragma unroll
                for (int t = 0; t < 4; ++t) {
                    const int kb = 32 * t + 8 * gg, n = 16 * nt + cc;
                    uint4 u;
                    u.x = pkbf(hw2[(kb + 0) * 32 + n], hw2[(kb + 1) * 32 + n]);
                    u.y = pkbf(hw2[(kb + 2) * 32 + n], hw2[(kb + 3) * 32 + n]);
                    u.z = pkbf(hw2[(kb + 4) * 32 + n], hw2[(kb + 5) * 32 + n]);
                    u.w = pkbf(hw2[(kb + 6) * 32 + n], hw2[(kb + 7) * 32 + n]);
                    fragW[(nt * 4 + t) * 64 + threadIdx.x] = u;
                }
            uint4 u;
            u.x = pkbf(gw1[(8 * gg + 0) * 16 + cc], gw1[(8 * gg + 1) * 16 + cc]);
            u.y = pkbf(gw1[(8 * gg + 2) * 16 + cc], gw1[(8 * gg + 3) * 16 + cc]);
            u.z = pkbf(gw1[(8 * gg + 4) * 16 + cc], gw1[(8 * gg + 5) * 16 + cc]);
            u.w = pkbf(gw1[(8 * gg + 6) * 16 + cc], gw1[(8 * gg + 7) * 16 + cc]);
            fragW[8 * 64 + threadIdx.x] = u;
        }
    }
}

// ---------------------------------------------------------------------------
// Kernel 1: per cell (b,j): pre -> LN1 -> relu -> (MFMA) @h_w2 -> +b2 -> LN2
// -> relu -> gates (MFMA + DPP all-reduce) -> exp(logit-10) -> weighted
// accumulation of head_sums in registers.  Wave = 1 j x 16 b.
// grid = (njb j-blocks, 8 b-tiles), block = 4 waves, jpw j's per wave.
// NOTE: (256,2): the (256,4) bound caps VGPRs at 64 and spills (R3: FETCH
// 5.4MB->343MB). NJB=128 (1024 blocks) = one fully-resident dispatch round
// (R5: NJB=256 -> 2-round tail, VALUBusy 70->41%, 109->180us).
// ---------------------------------------------------------------------------
__global__ __launch_bounds__(256, 2) void k_main(
    const float* __restrict__ x, const int* __restrict__ mask,
    const unsigned short* __restrict__ feWb, const float* __restrict__ aux,
    const float* __restrict__ scal, const uint4* __restrict__ fragW,
    const float* __restrict__ hw1, const float* __restrict__ ln1w,
    const float* __restrict__ ln1b,
    const float* __restrict__ hb2,
    const float* __restrict__ ln2w, const float* __restrict__ ln2b,
    const float* __restrict__ gb1,
    const float* __restrict__ gw2, const float* __restrict__ gb2,
    float* __restrict__ P, float* __restrict__ SEb, int njb, int jpw)
{
    __shared__ float w0s[128], g1s[128], b1s[128];
    __shared__ float holds[8][576];   // [wave*2+parity][16 rows x pitch 36]
    __shared__ float hsL[2048];
    __shared__ float seL[64];

    const int tid = threadIdx.x, l = tid & 63;
    const int wv = __builtin_amdgcn_readfirstlane(tid >> 6);
    const int c = l & 15, g = l >> 4;
    const int bt = blockIdx.y, bx = blockIdx.x;
    const int b0 = bt * 16;

    if (tid < 128) { w0s[tid] = hw1[tid]; g1s[tid] = ln1w[tid]; b1s[tid] = ln1b[tid]; }
    __syncthreads();

    const float mw0 = scal[0], q0 = scal[1];

    // pre-packed B-fragments: 9 coalesced dwordx4 loads (frag-major layout)
    s8x wf[2][4];
#pragma unroll
    for (int nt = 0; nt < 2; ++nt)
#pragma unroll
        for (int t = 0; t < 4; ++t)
            wf[nt][t] = __builtin_bit_cast(s8x, fragW[(nt * 4 + t) * 64 + l]);
    const s8x g1f = __builtin_bit_cast(s8x, fragW[8 * 64 + l]);

    const float hb2a = hb2[c],      hb2b = hb2[16 + c];
    const float g2a  = ln2w[c],     g2b  = ln2w[16 + c];
    const float z2a  = ln2b[c],     z2b  = ln2b[16 + c];
    const float gb1c = gb1[c];
    float gw2c[4], gb2v[4];
#pragma unroll
    for (int w = 0; w < 4; ++w) { gw2c[w] = gw2[c * 4 + w]; gb2v[w] = gb2[w]; }

    const int j0 = (bx * 4 + wv) * jpw;
    const float* xrow = x + (size_t)(b0 + c) * JDIM;
    const int*   mrow = mask + (size_t)(b0 + c) * JDIM;

    f2x   hsacc[4][4];   // [r][w] = {sum over nt=0, nt=1}
    float seacc[4][4];
#pragma unroll
    for (int r = 0; r < 4; ++r)
#pragma unroll
        for (int w = 0; w < 4; ++w) {
            hsacc[r][w].x = 0.f; hsacc[r][w].y = 0.f; seacc[r][w] = 0.f;
        }

    for (int jj = 0; jj < jpw; ++jj) {
        const int j = j0 + jj;
        const float xv = xrow[j];
        const int   mv = mrow[j];
        const float4 au = *(const float4*)(aux + j * 4);
        const float m1 = au.x, qx = au.y, q2 = au.z;
        const float mu = fmaf(xv, mw0, m1);
        const float e2 = fmaf(xv * xv, q0, fmaf(2.f * xv, qx, q2));
        const float rs = rsqrtf(e2 - mu * mu + 1e-5f);
        const float nms = -mu * rs;
        const f2x xv2 = {xv, xv}, rs2 = {rs, rs}, nm2 = {nms, nms};

        f4x ca = {0.f, 0.f, 0.f, 0.f}, cbv = {0.f, 0.f, 0.f, 0.f};
        const unsigned short* fj = feWb + (size_t)j * 128;
#pragma unroll
        for (int t = 0; t < 4; ++t) {
            const int kb = 32 * t + 8 * g;
            const uint4 fw = *(const uint4*)(fj + kb);
            const unsigned int fwv[4] = {fw.x, fw.y, fw.z, fw.w};
            const f2x* wp = (const f2x*)&w0s[kb];
            const f2x* gp = (const f2x*)&g1s[kb];
            const f2x* bp = (const f2x*)&b1s[kb];
            unsigned int res[4];
#pragma unroll
            for (int p = 0; p < 4; ++p) {
                f2x h2 = pkfma(xv2, wp[p], upk(fwv[p]));   // pre = xv*w0 + feW
                h2 = pkfma(h2, rs2, nm2);                  // (pre-mu)*rs
                h2 = pkfma(h2, gp[p], bp[p]);              // *g1 + b1
                h2 = pkmax0(h2);                           // relu
                res[p] = pkbf(h2.x, h2.y);
            }
            const uint4 u = make_uint4(res[0], res[1], res[2], res[3]);
            const s8x af = __builtin_bit_cast(s8x, u);
            ca  = __builtin_amdgcn_mfma_f32_16x16x32_bf16(af, wf[0][t], ca,  0, 0, 0);
            cbv = __builtin_amdgcn_mfma_f32_16x16x32_bf16(af, wf[1][t], cbv, 0, 0, 0);
        }

        // + h_b2, LN over D=32 (row = cell 4g+r across the 16-lane c-group)
        float v0[4], v1[4], sr[4], qr[4];
#pragma unroll
        for (int r = 0; r < 4; ++r) {
            v0[r] = ca[r] + hb2a;
            v1[r] = cbv[r] + hb2b;
            sr[r] = v0[r] + v1[r];
            qr[r] = v0[r] * v0[r] + v1[r] * v1[r];
        }
#pragma unroll
        for (int r = 0; r < 4; ++r) { sr[r] = allred16(sr[r]); qr[r] = allred16(qr[r]); }
        float ho0[4], ho1[4];
#pragma unroll
        for (int r = 0; r < 4; ++r) {
            const float m2  = sr[r] * 0.03125f;
            const float rs2b = rsqrtf(fmaf(qr[r], 0.03125f, -m2 * m2) + 1e-5f);
            const float nm2b = -m2 * rs2b;
            ho0[r] = fmaxf(fmaf(fmaf(v0[r], rs2b, nm2b), g2a, z2a), 0.f);
            ho1[r] = fmaxf(fmaf(fmaf(v1[r], rs2b, nm2b), g2b, z2b), 0.f);
        }

        // stage h_out into per-wave LDS (ping-pong), transpose-read A-frag
        float* hp = &holds[wv * 2 + (jj & 1)][0];
#pragma unroll
        for (int r = 0; r < 4; ++r) {
            hp[(4 * g + r) * 36 + c]      = ho0[r];
            hp[(4 * g + r) * 36 + 16 + c] = ho1[r];
        }
        asm volatile("s_waitcnt lgkmcnt(0)" ::: "memory");
        const float4 ra  = *(const float4*)&hp[c * 36 + 8 * g];
        const float4 rb2 = *(const float4*)&hp[c * 36 + 8 * g + 4];
        uint4 ua;
        ua.x = pkbf(ra.x, ra.y);  ua.y = pkbf(ra.z, ra.w);
        ua.z = pkbf(rb2.x, rb2.y); ua.w = pkbf(rb2.z, rb2.w);
        const s8x af2 = __builtin_bit_cast(s8x, ua);
        f4x gc = {0.f, 0.f, 0.f, 0.f};
        gc = __builtin_amdgcn_mfma_f32_16x16x32_bf16(af2, g1f, gc, 0, 0, 0);

        // gate2 partials + DPP all-reduce over the 16 m-lanes
        float pw[16];
#pragma unroll
        for (int r = 0; r < 4; ++r) {
            const float g1r = fmaxf(gc[r] + gb1c, 0.f);
#pragma unroll
            for (int w = 0; w < 4; ++w) pw[r * 4 + w] = g1r * gw2c[w];
        }
#pragma unroll
        for (int i = 0; i < 16; ++i) pw[i] = allred16(pw[i]);

        // mask bits via ballot (lanes 0..15 hold cells 0..15)
        const unsigned bm = (unsigned)__ballot(mv > 0);
        float fm[4];
#pragma unroll
        for (int r = 0; r < 4; ++r) fm[r] = (float)((bm >> (4 * g + r)) & 1u);

#pragma unroll
        for (int r = 0; r < 4; ++r) {
            const f2x ho2 = {ho0[r], ho1[r]};
#pragma unroll
            for (int w = 0; w < 4; ++w) {
                const float lg = __builtin_amdgcn_fmed3f(pw[r * 4 + w] + gb2v[w], -10.f, 10.f);
                const float e  = fm[r] * __builtin_amdgcn_exp2f(
                                     fmaf(lg, 1.44269504089f, -14.4269504089f));
                seacc[r][w] += e;
                const f2x e2v = {e, e};
                hsacc[r][w] = pkfma(e2v, ho2, hsacc[r][w]);
            }
        }
    }

    // combine the 4 waves' partials in LDS (barrier ladder, no atomics)
    for (int ww = 0; ww < 4; ++ww) {
        __syncthreads();
        if (wv == ww) {
#pragma unroll
            for (int r = 0; r < 4; ++r)
#pragma unroll
                for (int w = 0; w < 4; ++w)
#pragma unroll
                    for (int nt = 0; nt < 2; ++nt) {
                        const int idx = ((4 * g + r) * 4 + w) * 32 + c + 16 * nt;
                        const float val = nt ? hsacc[r][w].y : hsacc[r][w].x;
                        if (ww == 0) hsL[idx] = val;
                        else         hsL[idx] += val;
                    }
            if (c == 0) {
#pragma unroll
                for (int r = 0; r < 4; ++r)
#pragma unroll
                    for (int w = 0; w < 4; ++w) {
                        const int si = (4 * g + r) * 4 + w;
                        if (ww == 0) seL[si] = seacc[r][w];
                        else         seL[si] += seacc[r][w];
                    }
            }
        }
    }
    __syncthreads();
    const size_t base = ((size_t)bt * njb + bx) * 2048;
    for (int i = tid; i < 2048; i += 256) P[base + i] = hsL[i];
    if (tid < 64) SEb[((size_t)bt * njb + bx) * 64 + tid] = seL[tid];
}

// ---------------------------------------------------------------------------
// Kernel 2: per b: reduce the njb j-block partials, head_sums = hs/sumexp,
// comb = relu(LN(hs @ c_w + c_b)) (zeroed if no unmasked j), then the two
// e-layers with LN + relu, split into mu / logvar.
// ---------------------------------------------------------------------------
__global__ __launch_bounds__(128) void k_tail(
    const float* __restrict__ P, const float* __restrict__ SEb,
    const float* __restrict__ cw, const float* __restrict__ cbv,
    const float* __restrict__ clnw, const float* __restrict__ clnb,
    const float* __restrict__ ew1, const float* __restrict__ eb1,
    const float* __restrict__ l1w, const float* __restrict__ l1b,
    const float* __restrict__ ew2, const float* __restrict__ eb2,
    const float* __restrict__ l2w, const float* __restrict__ l2b,
    float* __restrict__ out, int njb)
{
    const int b = blockIdx.x, t = threadIdx.x;
    const int bt = b >> 4, bi = b & 15;
    __shared__ float hsLs[128], combL[32], hL[256], seW[4], sred[64], red[4];

    const float* Pb = P + (size_t)bt * njb * 2048 + bi * 128;
    float sacc = 0.f;
#pragma unroll 4
    for (int jc = 0; jc < njb; ++jc) sacc += Pb[(size_t)jc * 2048 + t];

    if (t < 64) {
        const int w = t & 3, part = t >> 2;
        float sp = 0.f;
        for (int q = part; q < njb; q += 16)
            sp += SEb[((size_t)bt * njb + q) * 64 + bi * 4 + w];
        sred[t] = sp;
    }
    __syncthreads();
    if (t < 4) {
        float v = 0.f;
#pragma unroll
        for (int sl = 0; sl < 16; ++sl) v += sred[sl * 4 + t];
        seW[t] = v;
    }
    __syncthreads();
    const bool has = seW[0] > 0.f;
    hsLs[t] = has ? sacc / seW[t >> 5] : 0.f;
    __syncthreads();

    if (t < 32) {
        float cv = cbv[t];
#pragma unroll 4
        for (int f = 0; f < 128; ++f) cv = fmaf(hsLs[f], cw[f * 32 + t], cv);
        float s = cv, q = cv * cv;
#pragma unroll
        for (int m = 1; m <= 16; m <<= 1) { s += __shfl_xor(s, m); q += __shfl_xor(q, m); }
        const float mu = s * (1.f / 32.f);
        const float rsg = rsqrtf(fmaf(q, 1.f / 32.f, -mu * mu) + 1e-5f);
        const float v = fmaf(fmaf(cv, rsg, -mu * rsg), clnw[t], clnb[t]);
        combL[t] = has ? fmaxf(v, 0.f) : 0.f;
    }
    __syncthreads();

    float h0 = eb1[t], h1v = eb1[t + 128];
#pragma unroll 4
    for (int d = 0; d < 32; ++d) {
        const float cd = combL[d];
        h0  = fmaf(cd, ew1[d * 256 + t], h0);
        h1v = fmaf(cd, ew1[d * 256 + t + 128], h1v);
    }
    {
        float s = h0 + h1v, q = h0 * h0 + h1v * h1v;
#pragma unroll
        for (int m = 1; m <= 32; m <<= 1) { s += __shfl_xor(s, m); q += __shfl_xor(q, m); }
        const int wv = t >> 6, ln = t & 63;
        if (ln == 0) { red[wv * 2] = s; red[wv * 2 + 1] = q; }
    }
    __syncthreads();
    {
        const float S = red[0] + red[2], Q = red[1] + red[3];
        const float mu1 = S * (1.f / 256.f);
        const float rs1 = rsqrtf(fmaf(Q, 1.f / 256.f, -mu1 * mu1) + 1e-5f);
        hL[t]       = fmaxf(fmaf(fmaf(h0,  rs1, -mu1 * rs1), l1w[t],       l1b[t]),       0.f);
        hL[t + 128] = fmaxf(fmaf(fmaf(h1v, rs1, -mu1 * rs1), l1w[t + 128], l1b[t + 128]), 0.f);
    }
    __syncthreads();

    if (t < 64) {
        float ov = eb2[t];
#pragma unroll 4
        for (int m = 0; m < 256; ++m) ov = fmaf(hL[m], ew2[m * 64 + t], ov);
        float s = ov, q = ov * ov;
#pragma unroll
        for (int m = 1; m <= 32; m <<= 1) { s += __shfl_xor(s, m); q += __shfl_xor(q, m); }
        const float mu2 = s * (1.f / 64.f);
        const float rs2 = rsqrtf(fmaf(q, 1.f / 64.f, -mu2 * mu2) + 1e-5f);
        const float o = fmaxf(fmaf(fmaf(ov, rs2, -mu2 * rs2), l2w[t], l2b[t]), 0.f);
        if (t < 32) out[b * 32 + t] = o;
        else        out[4096 + b * 32 + (t - 32)] = o;
    }
}

// ---------------------------------------------------------------------------
extern "C" void kernel_launch(void* const* d_in, const int* in_sizes, int n_in,
                              void* d_out, int out_size, void* d_ws, size_t ws_size,
                              hipStream_t stream)
{
    (void)in_sizes; (void)n_in; (void)out_size;
    const float* x    = (const float*)d_in[0];
    const int*   mask = (const int*)d_in[1];
    const float* fe   = (const float*)d_in[2];
    const float* hw1  = (const float*)d_in[3];
    const float* hb1  = (const float*)d_in[4];
    const float* ln1w = (const float*)d_in[5];
    const float* ln1b = (const float*)d_in[6];
    const float* hw2  = (const float*)d_in[7];
    const float* hb2  = (const float*)d_in[8];
    const float* ln2w = (const float*)d_in[9];
    const float* ln2b = (const float*)d_in[10];
    const float* gw1  = (const float*)d_in[11];
    const float* gb1  = (const float*)d_in[12];
    const float* gw2  = (const float*)d_in[13];
    const float* gb2  = (const float*)d_in[14];
    const float* cw   = (const float*)d_in[15];
    const float* cbv  = (const float*)d_in[16];
    const float* clnw = (const float*)d_in[17];
    const float* clnb = (const float*)d_in[18];
    const float* ew1  = (const float*)d_in[19];
    const float* eb1  = (const float*)d_in[20];
    const float* l1w  = (const float*)d_in[21];
    const float* l1b  = (const float*)d_in[22];
    const float* ew2  = (const float*)d_in[23];
    const float* eb2  = (const float*)d_in[24];
    const float* l2w  = (const float*)d_in[25];
    const float* l2b  = (const float*)d_in[26];

    const size_t fragOff = (2u << 20) + (128u << 10) + 256u;          // after feWb+aux+scal
    const size_t base    = fragOff + 9u * 64u * 16u;                  // + 9KB fragments
    // NJB=128 -> 1024 blocks = one fully-resident dispatch round (4 blocks/CU)
    int NJB = 128;
    {
        const size_t need = base + (size_t)8 * 128 * 2048 * 4 + (size_t)8 * 128 * 64 * 4;
        if (ws_size < need) NJB = 64;
    }
    const int JPW = JDIM / (NJB * 4);

    char* ws = (char*)d_ws;
    unsigned short* feWb = (unsigned short*)ws;                       // 2 MB
    float* aux   = (float*)(ws + (2u << 20));                         // 128 KB
    float* scal  = (float*)(ws + (2u << 20) + (128u << 10));          // 256 B
    uint4* fragW = (uint4*)(ws + fragOff);                            // 9 KB
    float* P     = (float*)(ws + base);                               // 8*NJB*2048*4 B
    float* SEb   = (float*)(ws + base + (size_t)8 * NJB * 2048 * 4);  // 8*NJB*64*4 B

    hipLaunchKernelGGL(k_prep, dim3(JDIM), dim3(128), 0, stream,
                       fe, hw1, hb1, hw2, gw1, feWb, aux, scal, fragW);
    hipLaunchKernelGGL(k_main, dim3(NJB, 8), dim3(256), 0, stream,
                       x, mask, feWb, aux, scal, fragW,
                       hw1, ln1w, ln1b, hb2, ln2w, ln2b,
                       gb1, gw2, gb2, P, SEb, NJB, JPW);
    hipLaunchKernelGGL(k_tail, dim3(BDIM), dim3(128), 0, stream,
                       P, SEb, cw, cbv, clnw, clnb,
                       ew1, eb1, l1w, l1b, ew2, eb2, l2w, l2b,
                       (float*)d_out, NJB);
}

// Round 9
// 237.270 us; speedup vs baseline: 1.4091x; 1.0425x over previous
//
#include <hip/hip_runtime.h>
#include <cstdint>

// Problem constants (reference: B,J,D,W,H,EH,L = 128,8192,32,4,128,256,32)
#define BDIM 128
#define JDIM 8192

typedef short s8x __attribute__((ext_vector_type(8)));   // 8 bf16 in 4 VGPRs (MFMA A/B frag)
typedef float f4x __attribute__((ext_vector_type(4)));   // MFMA C/D frag
typedef float f2x __attribute__((ext_vector_type(2)));   // packed-f32 (v_pk_*_f32)

// f32 -> bf16 via scalar casts: compiler fuses pairs into v_cvt_pk_bf16_f32.
__device__ __forceinline__ unsigned short bf16u(float f) {
    return __builtin_bit_cast(unsigned short, (__bf16)f);
}
__device__ __forceinline__ unsigned int pkbf(float lo, float hi) {
    return (unsigned int)bf16u(lo) | ((unsigned int)bf16u(hi) << 16);
}
// unpack a bf16 pair (lo,hi) -> f2x
__device__ __forceinline__ f2x upk(unsigned int w) {
    f2x r;
    r.x = __uint_as_float(w << 16);
    r.y = __uint_as_float(w & 0xffff0000u);
    return r;
}
__device__ __forceinline__ f2x pkfma(f2x a, f2x b, f2x c) {
    return __builtin_elementwise_fma(a, b, c);
}
__device__ __forceinline__ f2x pkmax0(f2x a) {
    f2x z = {0.f, 0.f};
    return __builtin_elementwise_max(a, z);
}

// 16-lane all-reduce sum, each stage ONE v_add_f32 with DPP on src0
// (asm guarantees the fused form; update_dpp+add may emit mov_dpp+add).
__device__ __forceinline__ float allred16(float x) {
    float t;
    asm("v_add_f32 %0, %1, %1 quad_perm:[1,0,3,2] row_mask:0xf bank_mask:0xf"
        : "=v"(t) : "v"(x));            // lane ^ 1
    asm("v_add_f32 %0, %1, %1 quad_perm:[2,3,0,1] row_mask:0xf bank_mask:0xf"
        : "=v"(x) : "v"(t));            // lane ^ 2
    asm("v_add_f32 %0, %1, %1 row_half_mirror row_mask:0xf bank_mask:0xf"
        : "=v"(t) : "v"(x));            // lane ^ 7
    asm("v_add_f32 %0, %1, %1 row_mirror row_mask:0xf bank_mask:0xf"
        : "=v"(x) : "v"(t));            // lane ^ 15
    return x;
}

// ---------------------------------------------------------------------------
// Kernel 0: 1024 blocks x 8 j: feW[j][h] (bf16) + per-j LN1 moments; block 0
// also writes mean(w0), mean(w0^2) and pre-packed MFMA B-fragments.
// ---------------------------------------------------------------------------
__global__ __launch_bounds__(128) void k_prep(
    const float* __restrict__ fe, const float* __restrict__ hw1,
    const float* __restrict__ hb1,
    const float* __restrict__ hw2, const float* __restrict__ gw1,
    unsigned short* __restrict__ feWb, float* __restrict__ aux,
    float* __restrict__ scal, uint4* __restrict__ fragW)
{
    const int h = threadIdx.x;
    __shared__ float red[2][3];
    const int wv = h >> 6, ln = h & 63;
    float w1r[32];
#pragma unroll
    for (int d = 0; d < 32; ++d) w1r[d] = hw1[(1 + d) * 128 + h];
    const float hb = hb1[h];
    const float w0h = hw1[h];

    for (int q = 0; q < 8; ++q) {
        const int j = blockIdx.x * 8 + q;
        float acc = hb;
#pragma unroll
        for (int d = 0; d < 32; ++d) acc = fmaf(fe[j * 32 + d], w1r[d], acc);
        feWb[(size_t)j * 128 + h] = bf16u(acc);

        float s1 = acc, sx = w0h * acc, s2 = acc * acc;
#pragma unroll
        for (int m = 1; m <= 32; m <<= 1) {
            s1 += __shfl_xor(s1, m); sx += __shfl_xor(sx, m); s2 += __shfl_xor(s2, m);
        }
        if (q) __syncthreads();                 // protect red[] reuse
        if (ln == 0) { red[wv][0] = s1; red[wv][1] = sx; red[wv][2] = s2; }
        __syncthreads();
        if (h == 0) {
            aux[j * 4 + 0] = (red[0][0] + red[1][0]) * (1.f / 128.f);
            aux[j * 4 + 1] = (red[0][1] + red[1][1]) * (1.f / 128.f);
            aux[j * 4 + 2] = (red[0][2] + red[1][2]) * (1.f / 128.f);
        }
    }

    if (blockIdx.x == 0) {
        float a = w0h, b = w0h * w0h;
#pragma unroll
        for (int m = 1; m <= 32; m <<= 1) { a += __shfl_xor(a, m); b += __shfl_xor(b, m); }
        __syncthreads();
        if (ln == 0) { red[wv][0] = a; red[wv][1] = b; }
        __syncthreads();
        if (h == 0) {
            scal[0] = (red[0][0] + red[1][0]) * (1.f / 128.f);
            scal[1] = (red[0][1] + red[1][1]) * (1.f / 128.f);
        }
        // pre-pack per-lane MFMA fragments: [frag][lane], coalesced in k_main.
        if (h < 64) {
            const int cc = h & 15, gg = h >> 4;
#pragma unroll
            for (int nt = 0; nt < 2; ++nt)
#pragma unroll
                for (int t = 0; t < 4; ++t) {
                    const int kb = 32 * t + 8 * gg, n = 16 * nt + cc;
                    uint4 u;
                    u.x = pkbf(hw2[(kb + 0) * 32 + n], hw2[(kb + 1) * 32 + n]);
                    u.y = pkbf(hw2[(kb + 2) * 32 + n], hw2[(kb + 3) * 32 + n]);
                    u.z = pkbf(hw2[(kb + 4) * 32 + n], hw2[(kb + 5) * 32 + n]);
                    u.w = pkbf(hw2[(kb + 6) * 32 + n], hw2[(kb + 7) * 32 + n]);
                    fragW[(nt * 4 + t) * 64 + h] = u;
                }
            uint4 u;
            u.x = pkbf(gw1[(8 * gg + 0) * 16 + cc], gw1[(8 * gg + 1) * 16 + cc]);
            u.y = pkbf(gw1[(8 * gg + 2) * 16 + cc], gw1[(8 * gg + 3) * 16 + cc]);
            u.z = pkbf(gw1[(8 * gg + 4) * 16 + cc], gw1[(8 * gg + 5) * 16 + cc]);
            u.w = pkbf(gw1[(8 * gg + 6) * 16 + cc], gw1[(8 * gg + 7) * 16 + cc]);
            fragW[8 * 64 + h] = u;
        }
    }
}

// ---------------------------------------------------------------------------
// Kernel 1: per cell (b,j): pre -> LN1 -> relu -> (MFMA) @h_w2 -> +b2 -> LN2
// -> relu -> gates (MFMA + DPP all-reduce) -> exp(logit-10) -> weighted
// accumulation in registers.  Wave = 1 j x 16 b, 2 j's in flight (ILP).
// grid = (njb, 8), block = 4 waves.  (256,2): (256,4) spills (R3).
// NJB=128 -> 1024 blocks = one fully-resident round (R5: 2048 regressed).
// ---------------------------------------------------------------------------
template <int JPW>
__global__ __launch_bounds__(256, 2) void k_main(
    const float* __restrict__ x, const int* __restrict__ mask,
    const unsigned short* __restrict__ feWb, const float* __restrict__ aux,
    const float* __restrict__ scal, const uint4* __restrict__ fragW,
    const float* __restrict__ hw1, const float* __restrict__ ln1w,
    const float* __restrict__ ln1b,
    const float* __restrict__ hb2,
    const float* __restrict__ ln2w, const float* __restrict__ ln2b,
    const float* __restrict__ gb1,
    const float* __restrict__ gw2, const float* __restrict__ gb2,
    float* __restrict__ P, float* __restrict__ SEb, int njb)
{
    __shared__ float w0s[128], g1s[128], b1s[128];
    __shared__ float holds[8][576];   // [wave*2+pair][16 rows x pitch 36]
    __shared__ float hsL[2048];
    __shared__ float seL[64];

    const int tid = threadIdx.x, l = tid & 63;
    const int wv = __builtin_amdgcn_readfirstlane(tid >> 6);
    const int c = l & 15, g = l >> 4;
    const int bt = blockIdx.y, bx = blockIdx.x;
    const int b0 = bt * 16;

    if (tid < 128) { w0s[tid] = hw1[tid]; g1s[tid] = ln1w[tid]; b1s[tid] = ln1b[tid]; }
    __syncthreads();

    const float mw0 = scal[0], q0 = scal[1];

    // pre-packed B-fragments: 9 coalesced dwordx4 loads
    s8x wf[2][4];
#pragma unroll
    for (int nt = 0; nt < 2; ++nt)
#pragma unroll
        for (int t = 0; t < 4; ++t)
            wf[nt][t] = __builtin_bit_cast(s8x, fragW[(nt * 4 + t) * 64 + l]);
    const s8x g1f = __builtin_bit_cast(s8x, fragW[8 * 64 + l]);

    const float hb2a = hb2[c],      hb2b = hb2[16 + c];
    const float g2a  = ln2w[c],     g2b  = ln2w[16 + c];
    const float z2a  = ln2b[c],     z2b  = ln2b[16 + c];
    const float gb1c = gb1[c];
    const float L2E  = 1.442695040888963f;
    float gw2c[4], gb2l[4];
#pragma unroll
    for (int w = 0; w < 4; ++w) {
        gw2c[w] = gw2[c * 4 + w];
        gb2l[w] = fmaf(gb2[w], L2E, -10.f * L2E);   // fold (+gb2, -10)*log2e
    }

    const int j0 = (bx * 4 + wv) * JPW;
    const float* xrow = x + (size_t)(b0 + c) * JDIM;
    const int*   mrow = mask + (size_t)(b0 + c) * JDIM;

    f2x   hsacc[4][4];   // [r][w] = {sum nt=0, nt=1}
    float seacc[4][4];
#pragma unroll
    for (int r = 0; r < 4; ++r)
#pragma unroll
        for (int w = 0; w < 4; ++w) {
            hsacc[r][w].x = 0.f; hsacc[r][w].y = 0.f; seacc[r][w] = 0.f;
        }

    for (int jp = 0; jp < JPW / 2; ++jp) {
        const int jb = j0 + jp * 2;

        // ---- phase A: per-j scalars (both j's) ----
        float xv[2], rsv[2], nms[2]; int mv[2];
#pragma unroll
        for (int p = 0; p < 2; ++p) {
            xv[p] = xrow[jb + p];
            mv[p] = mrow[jb + p];
            const float4 au = *(const float4*)(aux + (size_t)(jb + p) * 4);
            const float mu = fmaf(xv[p], mw0, au.x);
            const float e2 = fmaf(xv[p] * xv[p], q0, fmaf(2.f * xv[p], au.y, au.z));
            rsv[p] = rsqrtf(e2 - mu * mu + 1e-5f);
            nms[p] = -mu * rsv[p];
        }

        // ---- phase B: h-compute + h_w2 MFMAs (both j's, independent chains) ----
        f4x ca[2], cb[2];
#pragma unroll
        for (int p = 0; p < 2; ++p) { ca[p] = f4x{0.f,0.f,0.f,0.f}; cb[p] = f4x{0.f,0.f,0.f,0.f}; }
#pragma unroll
        for (int p = 0; p < 2; ++p) {
            const f2x xv2 = {xv[p], xv[p]}, rs2 = {rsv[p], rsv[p]}, nm2 = {nms[p], nms[p]};
            const unsigned short* fj = feWb + (size_t)(jb + p) * 128;
#pragma unroll
            for (int t = 0; t < 4; ++t) {
                const int kb = 32 * t + 8 * g;
                const uint4 fw = *(const uint4*)(fj + kb);
                const unsigned int fwv[4] = {fw.x, fw.y, fw.z, fw.w};
                const f2x* wp = (const f2x*)&w0s[kb];
                const f2x* gp = (const f2x*)&g1s[kb];
                const f2x* bp = (const f2x*)&b1s[kb];
                unsigned int res[4];
#pragma unroll
                for (int q = 0; q < 4; ++q) {
                    f2x h2 = pkfma(xv2, wp[q], upk(fwv[q]));   // pre = xv*w0 + feW
                    h2 = pkfma(h2, rs2, nm2);                  // (pre-mu)*rs
                    h2 = pkfma(h2, gp[q], bp[q]);              // *g1 + b1
                    h2 = pkmax0(h2);                           // relu
                    res[q] = pkbf(h2.x, h2.y);
                }
                const uint4 u = make_uint4(res[0], res[1], res[2], res[3]);
                const s8x af = __builtin_bit_cast(s8x, u);
                ca[p] = __builtin_amdgcn_mfma_f32_16x16x32_bf16(af, wf[0][t], ca[p], 0, 0, 0);
                cb[p] = __builtin_amdgcn_mfma_f32_16x16x32_bf16(af, wf[1][t], cb[p], 0, 0, 0);
            }
        }

        // ---- phase C: +b2, LN2 (DPP reduce), relu ----
        float ho0[2][4], ho1[2][4];
#pragma unroll
        for (int p = 0; p < 2; ++p) {
            float v0[4], v1[4], sr[4], qr[4];
#pragma unroll
            for (int r = 0; r < 4; ++r) {
                v0[r] = ca[p][r] + hb2a;
                v1[r] = cb[p][r] + hb2b;
                sr[r] = v0[r] + v1[r];
                qr[r] = v0[r] * v0[r] + v1[r] * v1[r];
            }
#pragma unroll
            for (int r = 0; r < 4; ++r) { sr[r] = allred16(sr[r]); qr[r] = allred16(qr[r]); }
#pragma unroll
            for (int r = 0; r < 4; ++r) {
                const float m2   = sr[r] * 0.03125f;
                const float rs2b = rsqrtf(fmaf(qr[r], 0.03125f, -m2 * m2) + 1e-5f);
                const float nm2b = -m2 * rs2b;
                ho0[p][r] = fmaxf(fmaf(fmaf(v0[r], rs2b, nm2b), g2a, z2a), 0.f);
                ho1[p][r] = fmaxf(fmaf(fmaf(v1[r], rs2b, nm2b), g2b, z2b), 0.f);
            }
        }

        // ---- phase D: LDS transpose bounce (both j's, one wait) + gate MFMA ----
#pragma unroll
        for (int p = 0; p < 2; ++p) {
            float* hp = &holds[wv * 2 + p][0];
#pragma unroll
            for (int r = 0; r < 4; ++r) {
                hp[(4 * g + r) * 36 + c]      = ho0[p][r];
                hp[(4 * g + r) * 36 + 16 + c] = ho1[p][r];
            }
        }
        asm volatile("s_waitcnt lgkmcnt(0)" ::: "memory");
        f4x gc[2];
#pragma unroll
        for (int p = 0; p < 2; ++p) {
            const float* hp = &holds[wv * 2 + p][0];
            const float4 ra  = *(const float4*)&hp[c * 36 + 8 * g];
            const float4 rb2 = *(const float4*)&hp[c * 36 + 8 * g + 4];
            uint4 ua;
            ua.x = pkbf(ra.x, ra.y);   ua.y = pkbf(ra.z, ra.w);
            ua.z = pkbf(rb2.x, rb2.y); ua.w = pkbf(rb2.z, rb2.w);
            const s8x af2 = __builtin_bit_cast(s8x, ua);
            f4x z = {0.f, 0.f, 0.f, 0.f};
            gc[p] = __builtin_amdgcn_mfma_f32_16x16x32_bf16(af2, g1f, z, 0, 0, 0);
        }

        // ---- phase E: gate2 reduce + exp (log2-domain) + weighted accum ----
#pragma unroll
        for (int p = 0; p < 2; ++p) {
            float pw[16];
#pragma unroll
            for (int r = 0; r < 4; ++r) {
                const float g1r = fmaxf(gc[p][r] + gb1c, 0.f);
#pragma unroll
                for (int w = 0; w < 4; ++w) pw[r * 4 + w] = g1r * gw2c[w];
            }
#pragma unroll
            for (int i = 0; i < 16; ++i) pw[i] = allred16(pw[i]);

            const unsigned bm = (unsigned)__ballot(mv[p] > 0);
            float fm[4];
#pragma unroll
            for (int r = 0; r < 4; ++r) fm[r] = (float)((bm >> (4 * g + r)) & 1u);

#pragma unroll
            for (int r = 0; r < 4; ++r) {
                const f2x ho2 = {ho0[p][r], ho1[p][r]};
#pragma unroll
                for (int w = 0; w < 4; ++w) {
                    float t = fmaf(pw[r * 4 + w], L2E, gb2l[w]);
                    t = __builtin_amdgcn_fmed3f(t, -20.f * L2E, 0.f);
                    const float e = fm[r] * __builtin_amdgcn_exp2f(t);
                    seacc[r][w] += e;
                    const f2x e2v = {e, e};
                    hsacc[r][w] = pkfma(e2v, ho2, hsacc[r][w]);
                }
            }
        }
    }

    // combine the 4 waves' partials in LDS (barrier ladder, no atomics)
    for (int ww = 0; ww < 4; ++ww) {
        __syncthreads();
        if (wv == ww) {
#pragma unroll
            for (int r = 0; r < 4; ++r)
#pragma unroll
                for (int w = 0; w < 4; ++w)
#pragma unroll
                    for (int nt = 0; nt < 2; ++nt) {
                        const int idx = ((4 * g + r) * 4 + w) * 32 + c + 16 * nt;
                        const float val = nt ? hsacc[r][w].y : hsacc[r][w].x;
                        if (ww == 0) hsL[idx] = val;
                        else         hsL[idx] += val;
                    }
            if (c == 0) {
#pragma unroll
                for (int r = 0; r < 4; ++r)
#pragma unroll
                    for (int w = 0; w < 4; ++w) {
                        const int si = (4 * g + r) * 4 + w;
                        if (ww == 0) seL[si] = seacc[r][w];
                        else         seL[si] += seacc[r][w];
                    }
            }
        }
    }
    __syncthreads();
    const size_t base = ((size_t)bt * njb + bx) * 2048;
    for (int i = tid; i < 2048; i += 256) P[base + i] = hsL[i];
    if (tid < 64) SEb[((size_t)bt * njb + bx) * 64 + tid] = seL[tid];
}

// ---------------------------------------------------------------------------
// Kernel 2: per b: reduce partials, head_sums = hs/sumexp, comb-LN-relu,
// two e-layers with LN + relu, split mu / logvar.
// ---------------------------------------------------------------------------
__global__ __launch_bounds__(128) void k_tail(
    const float* __restrict__ P, const float* __restrict__ SEb,
    const float* __restrict__ cw, const float* __restrict__ cbv,
    const float* __restrict__ clnw, const float* __restrict__ clnb,
    const float* __restrict__ ew1, const float* __restrict__ eb1,
    const float* __restrict__ l1w, const float* __restrict__ l1b,
    const float* __restrict__ ew2, const float* __restrict__ eb2,
    const float* __restrict__ l2w, const float* __restrict__ l2b,
    float* __restrict__ out, int njb)
{
    const int b = blockIdx.x, t = threadIdx.x;
    const int bt = b >> 4, bi = b & 15;
    __shared__ float hsLs[128], combL[32], hL[256], seW[4], sred[64], red[4];

    const float* Pb = P + (size_t)bt * njb * 2048 + bi * 128;
    float sacc = 0.f;
#pragma unroll 4
    for (int jc = 0; jc < njb; ++jc) sacc += Pb[(size_t)jc * 2048 + t];

    if (t < 64) {
        const int w = t & 3, part = t >> 2;
        float sp = 0.f;
        for (int q = part; q < njb; q += 16)
            sp += SEb[((size_t)bt * njb + q) * 64 + bi * 4 + w];
        sred[t] = sp;
    }
    __syncthreads();
    if (t < 4) {
        float v = 0.f;
#pragma unroll
        for (int sl = 0; sl < 16; ++sl) v += sred[sl * 4 + t];
        seW[t] = v;
    }
    __syncthreads();
    const bool has = seW[0] > 0.f;
    hsLs[t] = has ? sacc / seW[t >> 5] : 0.f;
    __syncthreads();

    if (t < 32) {
        float cv = cbv[t];
#pragma unroll 4
        for (int f = 0; f < 128; ++f) cv = fmaf(hsLs[f], cw[f * 32 + t], cv);
        float s = cv, q = cv * cv;
#pragma unroll
        for (int m = 1; m <= 16; m <<= 1) { s += __shfl_xor(s, m); q += __shfl_xor(q, m); }
        const float mu = s * (1.f / 32.f);
        const float rsg = rsqrtf(fmaf(q, 1.f / 32.f, -mu * mu) + 1e-5f);
        const float v = fmaf(fmaf(cv, rsg, -mu * rsg), clnw[t], clnb[t]);
        combL[t] = has ? fmaxf(v, 0.f) : 0.f;
    }
    __syncthreads();

    float h0 = eb1[t], h1v = eb1[t + 128];
#pragma unroll 4
    for (int d = 0; d < 32; ++d) {
        const float cd = combL[d];
        h0  = fmaf(cd, ew1[d * 256 + t], h0);
        h1v = fmaf(cd, ew1[d * 256 + t + 128], h1v);
    }
    {
        float s = h0 + h1v, q = h0 * h0 + h1v * h1v;
#pragma unroll
        for (int m = 1; m <= 32; m <<= 1) { s += __shfl_xor(s, m); q += __shfl_xor(q, m); }
        const int wv = t >> 6, ln = t & 63;
        if (ln == 0) { red[wv * 2] = s; red[wv * 2 + 1] = q; }
    }
    __syncthreads();
    {
        const float S = red[0] + red[2], Q = red[1] + red[3];
        const float mu1 = S * (1.f / 256.f);
        const float rs1 = rsqrtf(fmaf(Q, 1.f / 256.f, -mu1 * mu1) + 1e-5f);
        hL[t]       = fmaxf(fmaf(fmaf(h0,  rs1, -mu1 * rs1), l1w[t],       l1b[t]),       0.f);
        hL[t + 128] = fmaxf(fmaf(fmaf(h1v, rs1, -mu1 * rs1), l1w[t + 128], l1b[t + 128]), 0.f);
    }
    __syncthreads();

    if (t < 64) {
        float ov = eb2[t];
#pragma unroll 4
        for (int m = 0; m < 256; ++m) ov = fmaf(hL[m], ew2[m * 64 + t], ov);
        float s = ov, q = ov * ov;
#pragma unroll
        for (int m = 1; m <= 32; m <<= 1) { s += __shfl_xor(s, m); q += __shfl_xor(q, m); }
        const float mu2 = s * (1.f / 64.f);
        const float rs2 = rsqrtf(fmaf(q, 1.f / 64.f, -mu2 * mu2) + 1e-5f);
        const float o = fmaxf(fmaf(fmaf(ov, rs2, -mu2 * rs2), l2w[t], l2b[t]), 0.f);
        if (t < 32) out[b * 32 + t] = o;
        else        out[4096 + b * 32 + (t - 32)] = o;
    }
}

// ---------------------------------------------------------------------------
extern "C" void kernel_launch(void* const* d_in, const int* in_sizes, int n_in,
                              void* d_out, int out_size, void* d_ws, size_t ws_size,
                              hipStream_t stream)
{
    (void)in_sizes; (void)n_in; (void)out_size;
    const float* x    = (const float*)d_in[0];
    const int*   mask = (const int*)d_in[1];
    const float* fe   = (const float*)d_in[2];
    const float* hw1  = (const float*)d_in[3];
    const float* hb1  = (const float*)d_in[4];
    const float* ln1w = (const float*)d_in[5];
    const float* ln1b = (const float*)d_in[6];
    const float* hw2  = (const float*)d_in[7];
    const float* hb2  = (const float*)d_in[8];
    const float* ln2w = (const float*)d_in[9];
    const float* ln2b = (const float*)d_in[10];
    const float* gw1  = (const float*)d_in[11];
    const float* gb1  = (const float*)d_in[12];
    const float* gw2  = (const float*)d_in[13];
    const float* gb2  = (const float*)d_in[14];
    const float* cw   = (const float*)d_in[15];
    const float* cbv  = (const float*)d_in[16];
    const float* clnw = (const float*)d_in[17];
    const float* clnb = (const float*)d_in[18];
    const float* ew1  = (const float*)d_in[19];
    const float* eb1  = (const float*)d_in[20];
    const float* l1w  = (const float*)d_in[21];
    const float* l1b  = (const float*)d_in[22];
    const float* ew2  = (const float*)d_in[23];
    const float* eb2  = (const float*)d_in[24];
    const float* l2w  = (const float*)d_in[25];
    const float* l2b  = (const float*)d_in[26];

    const size_t fragOff = (2u << 20) + (128u << 10) + 256u;          // after feWb+aux+scal
    const size_t base    = fragOff + 9u * 64u * 16u;                  // + 9KB fragments
    // NJB=128 -> 1024 blocks = one fully-resident dispatch round
    int NJB = 128;
    {
        const size_t need = base + (size_t)8 * 128 * 2048 * 4 + (size_t)8 * 128 * 64 * 4;
        if (ws_size < need) NJB = 64;
    }

    char* ws = (char*)d_ws;
    unsigned short* feWb = (unsigned short*)ws;                       // 2 MB
    float* aux   = (float*)(ws + (2u << 20));                         // 128 KB
    float* scal  = (float*)(ws + (2u << 20) + (128u << 10));          // 256 B
    uint4* fragW = (uint4*)(ws + fragOff);                            // 9 KB
    float* P     = (float*)(ws + base);                               // 8*NJB*2048*4 B
    float* SEb   = (float*)(ws + base + (size_t)8 * NJB * 2048 * 4);  // 8*NJB*64*4 B

    hipLaunchKernelGGL(k_prep, dim3(JDIM / 8), dim3(128), 0, stream,
                       fe, hw1, hb1, hw2, gw1, feWb, aux, scal, fragW);
    if (NJB == 128)
        hipLaunchKernelGGL((k_main<16>), dim3(128, 8), dim3(256), 0, stream,
                           x, mask, feWb, aux, scal, fragW,
                           hw1, ln1w, ln1b, hb2, ln2w, ln2b,
                           gb1, gw2, gb2, P, SEb, 128);
    else
        hipLaunchKernelGGL((k_main<32>), dim3(64, 8), dim3(256), 0, stream,
                           x, mask, feWb, aux, scal, fragW,
                           hw1, ln1w, ln1b, hb2, ln2w, ln2b,
                           gb1, gw2, gb2, P, SEb, 64);
    hipLaunchKernelGGL(k_tail, dim3(BDIM), dim3(128), 0, stream,
                       P, SEb, cw, cbv, clnw, clnb,
                       ew1, eb1, l1w, l1b, ew2, eb2, l2w, l2b,
                       (float*)d_out, NJB);
}

// Round 10
// 221.464 us; speedup vs baseline: 1.5097x; 1.0714x over previous
//
#include <hip/hip_runtime.h>
#include <cstdint>

// Problem constants (reference: B,J,D,W,H,EH,L = 128,8192,32,4,128,256,32)
#define BDIM 128
#define JDIM 8192

typedef short s8x __attribute__((ext_vector_type(8)));   // 8 bf16 in 4 VGPRs (MFMA A/B frag)
typedef float f4x __attribute__((ext_vector_type(4)));   // MFMA C/D frag
typedef float f2x __attribute__((ext_vector_type(2)));   // packed-f32 (v_pk_*_f32)

// f32 -> bf16 via scalar casts: compiler fuses pairs into v_cvt_pk_bf16_f32.
__device__ __forceinline__ unsigned short bf16u(float f) {
    return __builtin_bit_cast(unsigned short, (__bf16)f);
}
__device__ __forceinline__ unsigned int pkbf(float lo, float hi) {
    return (unsigned int)bf16u(lo) | ((unsigned int)bf16u(hi) << 16);
}
// unpack a bf16 pair (lo,hi) -> f2x
__device__ __forceinline__ f2x upk(unsigned int w) {
    f2x r;
    r.x = __uint_as_float(w << 16);
    r.y = __uint_as_float(w & 0xffff0000u);
    return r;
}
__device__ __forceinline__ f2x pkfma(f2x a, f2x b, f2x c) {
    return __builtin_elementwise_fma(a, b, c);
}
__device__ __forceinline__ f2x pkmax0(f2x a) {
    f2x z = {0.f, 0.f};
    return __builtin_elementwise_max(a, z);
}

// 16-lane all-reduce sum, each stage ONE v_add_f32 with DPP on src0.
__device__ __forceinline__ float allred16(float x) {
    float t;
    asm("v_add_f32 %0, %1, %1 quad_perm:[1,0,3,2] row_mask:0xf bank_mask:0xf"
        : "=v"(t) : "v"(x));            // lane ^ 1
    asm("v_add_f32 %0, %1, %1 quad_perm:[2,3,0,1] row_mask:0xf bank_mask:0xf"
        : "=v"(x) : "v"(t));            // lane ^ 2
    asm("v_add_f32 %0, %1, %1 row_half_mirror row_mask:0xf bank_mask:0xf"
        : "=v"(t) : "v"(x));            // lane ^ 7
    asm("v_add_f32 %0, %1, %1 row_mirror row_mask:0xf bank_mask:0xf"
        : "=v"(x) : "v"(t));            // lane ^ 15
    return x;
}

// ---------------------------------------------------------------------------
// Kernel 0: 1024 blocks x 8 j: feW[j][h] (bf16) + per-j LN1 moments; block 0
// also writes mean(w0), mean(w0^2) and pre-packed MFMA B-fragments.
// ---------------------------------------------------------------------------
__global__ __launch_bounds__(128) void k_prep(
    const float* __restrict__ fe, const float* __restrict__ hw1,
    const float* __restrict__ hb1,
    const float* __restrict__ hw2, const float* __restrict__ gw1,
    unsigned short* __restrict__ feWb, float* __restrict__ aux,
    float* __restrict__ scal, uint4* __restrict__ fragW)
{
    const int h = threadIdx.x;
    __shared__ float red[2][3];
    const int wv = h >> 6, ln = h & 63;
    float w1r[32];
#pragma unroll
    for (int d = 0; d < 32; ++d) w1r[d] = hw1[(1 + d) * 128 + h];
    const float hb = hb1[h];
    const float w0h = hw1[h];

    for (int q = 0; q < 8; ++q) {
        const int j = blockIdx.x * 8 + q;
        float acc = hb;
#pragma unroll
        for (int d = 0; d < 32; ++d) acc = fmaf(fe[j * 32 + d], w1r[d], acc);
        feWb[(size_t)j * 128 + h] = bf16u(acc);

        float s1 = acc, sx = w0h * acc, s2 = acc * acc;
#pragma unroll
        for (int m = 1; m <= 32; m <<= 1) {
            s1 += __shfl_xor(s1, m); sx += __shfl_xor(sx, m); s2 += __shfl_xor(s2, m);
        }
        if (q) __syncthreads();                 // protect red[] reuse
        if (ln == 0) { red[wv][0] = s1; red[wv][1] = sx; red[wv][2] = s2; }
        __syncthreads();
        if (h == 0) {
            aux[j * 4 + 0] = (red[0][0] + red[1][0]) * (1.f / 128.f);
            aux[j * 4 + 1] = (red[0][1] + red[1][1]) * (1.f / 128.f);
            aux[j * 4 + 2] = (red[0][2] + red[1][2]) * (1.f / 128.f);
        }
    }

    if (blockIdx.x == 0) {
        float a = w0h, b = w0h * w0h;
#pragma unroll
        for (int m = 1; m <= 32; m <<= 1) { a += __shfl_xor(a, m); b += __shfl_xor(b, m); }
        __syncthreads();
        if (ln == 0) { red[wv][0] = a; red[wv][1] = b; }
        __syncthreads();
        if (h == 0) {
            scal[0] = (red[0][0] + red[1][0]) * (1.f / 128.f);
            scal[1] = (red[0][1] + red[1][1]) * (1.f / 128.f);
        }
        // pre-pack per-lane MFMA fragments: [frag][lane], coalesced in k_main.
        if (h < 64) {
            const int cc = h & 15, gg = h >> 4;
#pragma unroll
            for (int nt = 0; nt < 2; ++nt)
#pragma unroll
                for (int t = 0; t < 4; ++t) {
                    const int kb = 32 * t + 8 * gg, n = 16 * nt + cc;
                    uint4 u;
                    u.x = pkbf(hw2[(kb + 0) * 32 + n], hw2[(kb + 1) * 32 + n]);
                    u.y = pkbf(hw2[(kb + 2) * 32 + n], hw2[(kb + 3) * 32 + n]);
                    u.z = pkbf(hw2[(kb + 4) * 32 + n], hw2[(kb + 5) * 32 + n]);
                    u.w = pkbf(hw2[(kb + 6) * 32 + n], hw2[(kb + 7) * 32 + n]);
                    fragW[(nt * 4 + t) * 64 + h] = u;
                }
            uint4 u;
            u.x = pkbf(gw1[(8 * gg + 0) * 16 + cc], gw1[(8 * gg + 1) * 16 + cc]);
            u.y = pkbf(gw1[(8 * gg + 2) * 16 + cc], gw1[(8 * gg + 3) * 16 + cc]);
            u.z = pkbf(gw1[(8 * gg + 4) * 16 + cc], gw1[(8 * gg + 5) * 16 + cc]);
            u.w = pkbf(gw1[(8 * gg + 6) * 16 + cc], gw1[(8 * gg + 7) * 16 + cc]);
            fragW[8 * 64 + h] = u;
        }
    }
}

// ---------------------------------------------------------------------------
// Kernel 1: MFMA rows re-tiled as 4 cells x 4 j (row = cell*4 + j).
// Input side: lane c -> row c = (cell=c>>2, j=jb+(c&3)).
// Output side: C-reg r of lane-group g -> row 4g+r = (cell=g, j=jb+r).
// Per batch of 4 j: one pass of LN2 reduce, LDS bounce, gate MFMA, gate
// reduce + exp -> ~4x fewer per-j fixed costs than the 16-cell x 1-j tiling.
// grid = (32 jb, 32 bt) x 4 waves; 64 j per wave (16 batches).
// (256,2): (256,4) caps VGPR at 64 and spills (R3).
// ---------------------------------------------------------------------------
__global__ __launch_bounds__(256, 2) void k_main(
    const float* __restrict__ x, const int* __restrict__ mask,
    const unsigned short* __restrict__ feWb, const float* __restrict__ aux,
    const float* __restrict__ scal, const uint4* __restrict__ fragW,
    const float* __restrict__ hw1, const float* __restrict__ ln1w,
    const float* __restrict__ ln1b,
    const float* __restrict__ hb2,
    const float* __restrict__ ln2w, const float* __restrict__ ln2b,
    const float* __restrict__ gb1,
    const float* __restrict__ gw2, const float* __restrict__ gb2,
    float* __restrict__ P, float* __restrict__ SEb)
{
    __shared__ float w0s[128], g1s[128], b1s[128];
    __shared__ float holds[8][576];   // [wave*2+parity][16 rows x pitch 36]
    __shared__ float hsL[512];        // [cell=4][w=4][d=32]
    __shared__ float seL[16];

    const int tid = threadIdx.x, l = tid & 63;
    const int wv = __builtin_amdgcn_readfirstlane(tid >> 6);
    const int c = l & 15, g = l >> 4;
    const int bt = blockIdx.y, bx = blockIdx.x;
    const int b0 = bt * 4;
    const int cell_in = c >> 2, jsub = c & 3;   // input-side row decode

    if (tid < 128) { w0s[tid] = hw1[tid]; g1s[tid] = ln1w[tid]; b1s[tid] = ln1b[tid]; }
    __syncthreads();

    const float mw0 = scal[0], q0 = scal[1];

    // pre-packed B-fragments: 9 coalesced dwordx4 loads
    s8x wf[2][4];
#pragma unroll
    for (int nt = 0; nt < 2; ++nt)
#pragma unroll
        for (int t = 0; t < 4; ++t)
            wf[nt][t] = __builtin_bit_cast(s8x, fragW[(nt * 4 + t) * 64 + l]);
    const s8x g1f = __builtin_bit_cast(s8x, fragW[8 * 64 + l]);

    const float hb2a = hb2[c],      hb2b = hb2[16 + c];
    const float g2a  = ln2w[c],     g2b  = ln2w[16 + c];
    const float z2a  = ln2b[c],     z2b  = ln2b[16 + c];
    const float gb1c = gb1[c];
    const float L2E  = 1.442695040888963f;
    float gw2c[4], gb2l[4];
#pragma unroll
    for (int w = 0; w < 4; ++w) {
        gw2c[w] = gw2[c * 4 + w];
        gb2l[w] = fmaf(gb2[w], L2E, -10.f * L2E);   // fold (+gb2, -10)*log2e
    }

    const int j0 = (bx * 4 + wv) * 64;
    const float* xrow = x + (size_t)(b0 + cell_in) * JDIM;
    const int*   mrow = mask + (size_t)(b0 + cell_in) * JDIM;

    f2x   hsacc[4];    // [w] = {sum d=c, d=16+c} for cell=g
    float seacc[4];
#pragma unroll
    for (int w = 0; w < 4; ++w) { hsacc[w].x = 0.f; hsacc[w].y = 0.f; seacc[w] = 0.f; }

    for (int bi = 0; bi < 16; ++bi) {
        const int jb = j0 + bi * 4;
        const int j  = jb + jsub;

        // ---- phase A: per-lane LN1 scalars for row c's j ----
        const float xv = xrow[j];
        const int   mv = mrow[j];
        const float4 au = *(const float4*)(aux + (size_t)j * 4);
        const float mu = fmaf(xv, mw0, au.x);
        const float e2 = fmaf(xv * xv, q0, fmaf(2.f * xv, au.y, au.z));
        const float rs = rsqrtf(e2 - mu * mu + 1e-5f);
        const float nms = -mu * rs;
        const f2x xv2 = {xv, xv}, rs2 = {rs, rs}, nm2 = {nms, nms};

        // ---- phase B: h-compute for row c + h_w2 MFMAs (covers 4 j) ----
        f4x ca = {0.f, 0.f, 0.f, 0.f}, cb = {0.f, 0.f, 0.f, 0.f};
        const unsigned short* fj = feWb + (size_t)j * 128;
#pragma unroll
        for (int t = 0; t < 4; ++t) {
            const int kb = 32 * t + 8 * g;
            const uint4 fw = *(const uint4*)(fj + kb);
            const unsigned int fwv[4] = {fw.x, fw.y, fw.z, fw.w};
            const f2x* wp = (const f2x*)&w0s[kb];
            const f2x* gp = (const f2x*)&g1s[kb];
            const f2x* bp = (const f2x*)&b1s[kb];
            unsigned int res[4];
#pragma unroll
            for (int q = 0; q < 4; ++q) {
                f2x h2 = pkfma(xv2, wp[q], upk(fwv[q]));   // pre = xv*w0 + feW
                h2 = pkfma(h2, rs2, nm2);                  // (pre-mu)*rs
                h2 = pkfma(h2, gp[q], bp[q]);              // *g1 + b1
                h2 = pkmax0(h2);                           // relu
                res[q] = pkbf(h2.x, h2.y);
            }
            const uint4 u = make_uint4(res[0], res[1], res[2], res[3]);
            const s8x af = __builtin_bit_cast(s8x, u);
            ca = __builtin_amdgcn_mfma_f32_16x16x32_bf16(af, wf[0][t], ca, 0, 0, 0);
            cb = __builtin_amdgcn_mfma_f32_16x16x32_bf16(af, wf[1][t], cb, 0, 0, 0);
        }

        // ---- phase C: +b2, LN2 (DPP reduce over D), relu. rows 4g+r ----
        float v0[4], v1[4], sr[4], qr[4];
#pragma unroll
        for (int r = 0; r < 4; ++r) {
            v0[r] = ca[r] + hb2a;
            v1[r] = cb[r] + hb2b;
            sr[r] = v0[r] + v1[r];
            qr[r] = v0[r] * v0[r] + v1[r] * v1[r];
        }
#pragma unroll
        for (int r = 0; r < 4; ++r) { sr[r] = allred16(sr[r]); qr[r] = allred16(qr[r]); }
        float ho0[4], ho1[4];
#pragma unroll
        for (int r = 0; r < 4; ++r) {
            const float m2   = sr[r] * 0.03125f;
            const float rs2b = rsqrtf(fmaf(qr[r], 0.03125f, -m2 * m2) + 1e-5f);
            const float nm2b = -m2 * rs2b;
            ho0[r] = fmaxf(fmaf(fmaf(v0[r], rs2b, nm2b), g2a, z2a), 0.f);
            ho1[r] = fmaxf(fmaf(fmaf(v1[r], rs2b, nm2b), g2b, z2b), 0.f);
        }

        // ---- phase D: LDS transpose bounce + gate MFMA (covers 4 j) ----
        float* hp = &holds[wv * 2 + (bi & 1)][0];
#pragma unroll
        for (int r = 0; r < 4; ++r) {
            hp[(4 * g + r) * 36 + c]      = ho0[r];
            hp[(4 * g + r) * 36 + 16 + c] = ho1[r];
        }
        asm volatile("s_waitcnt lgkmcnt(0)" ::: "memory");
        const float4 ra  = *(const float4*)&hp[c * 36 + 8 * g];
        const float4 rb2 = *(const float4*)&hp[c * 36 + 8 * g + 4];
        uint4 ua;
        ua.x = pkbf(ra.x, ra.y);   ua.y = pkbf(ra.z, ra.w);
        ua.z = pkbf(rb2.x, rb2.y); ua.w = pkbf(rb2.z, rb2.w);
        const s8x af2 = __builtin_bit_cast(s8x, ua);
        f4x zz = {0.f, 0.f, 0.f, 0.f};
        const f4x gc = __builtin_amdgcn_mfma_f32_16x16x32_bf16(af2, g1f, zz, 0, 0, 0);

        // ---- phase E: gate2 reduce + exp + weighted accum (covers 4 j) ----
        float pw[16];
#pragma unroll
        for (int r = 0; r < 4; ++r) {
            const float g1r = fmaxf(gc[r] + gb1c, 0.f);
#pragma unroll
            for (int w = 0; w < 4; ++w) pw[r * 4 + w] = g1r * gw2c[w];
        }
#pragma unroll
        for (int i = 0; i < 16; ++i) pw[i] = allred16(pw[i]);

        const unsigned long long bm = __ballot(mv > 0);
#pragma unroll
        for (int r = 0; r < 4; ++r) {
            const float fm = (float)((bm >> (4 * g + r)) & 1ull);
            const f2x ho2 = {ho0[r], ho1[r]};
#pragma unroll
            for (int w = 0; w < 4; ++w) {
                float t2 = fmaf(pw[r * 4 + w], L2E, gb2l[w]);
                t2 = __builtin_amdgcn_fmed3f(t2, -20.f * L2E, 0.f);
                const float e = fm * __builtin_amdgcn_exp2f(t2);
                seacc[w] += e;
                const f2x e2v = {e, e};
                hsacc[w] = pkfma(e2v, ho2, hsacc[w]);
            }
        }
    }

    // combine the 4 waves' partials in LDS (barrier ladder)
    for (int ww = 0; ww < 4; ++ww) {
        __syncthreads();
        if (wv == ww) {
#pragma unroll
            for (int w = 0; w < 4; ++w)
#pragma unroll
                for (int nt = 0; nt < 2; ++nt) {
                    const int idx = (g * 4 + w) * 32 + 16 * nt + c;   // [cell][w][d]
                    const float val = nt ? hsacc[w].y : hsacc[w].x;
                    if (ww == 0) hsL[idx] = val;
                    else         hsL[idx] += val;
                }
            if (c == 0) {
#pragma unroll
                for (int w = 0; w < 4; ++w) {
                    const int si = g * 4 + w;
                    if (ww == 0) seL[si] = seacc[w];
                    else         seL[si] += seacc[w];
                }
            }
        }
    }
    __syncthreads();
    const size_t base = ((size_t)bt * 32 + bx) * 512;
    for (int i = tid; i < 512; i += 256) P[base + i] = hsL[i];
    if (tid < 16) SEb[((size_t)bt * 32 + bx) * 16 + tid] = seL[tid];
}

// ---------------------------------------------------------------------------
// Kernel 2: per b: reduce the 32 j-block partials, head_sums = hs/sumexp,
// comb-LN-relu, two e-layers with LN + relu, split mu / logvar.
// ---------------------------------------------------------------------------
__global__ __launch_bounds__(128) void k_tail(
    const float* __restrict__ P, const float* __restrict__ SEb,
    const float* __restrict__ cw, const float* __restrict__ cbv,
    const float* __restrict__ clnw, const float* __restrict__ clnb,
    const float* __restrict__ ew1, const float* __restrict__ eb1,
    const float* __restrict__ l1w, const float* __restrict__ l1b,
    const float* __restrict__ ew2, const float* __restrict__ eb2,
    const float* __restrict__ l2w, const float* __restrict__ l2b,
    float* __restrict__ out)
{
    const int b = blockIdx.x, t = threadIdx.x;
    const int bt = b >> 2, cell = b & 3;
    __shared__ float hsLs[128], combL[32], hL[256], seW[4], red[4];

    // hs partial: t -> (w = t>>5, d = t&31)
    const float* Pb = P + (size_t)bt * 32 * 512 + (size_t)(cell * 4 + (t >> 5)) * 32 + (t & 31);
    float sacc = 0.f;
#pragma unroll 4
    for (int q = 0; q < 32; ++q) sacc += Pb[(size_t)q * 512];

    if (t < 4) {
        float s = 0.f;
        for (int q = 0; q < 32; ++q) s += SEb[((size_t)bt * 32 + q) * 16 + cell * 4 + t];
        seW[t] = s;
    }
    __syncthreads();
    const bool has = seW[0] > 0.f;
    hsLs[t] = has ? sacc / seW[t >> 5] : 0.f;
    __syncthreads();

    if (t < 32) {
        float cv = cbv[t];
#pragma unroll 4
        for (int f = 0; f < 128; ++f) cv = fmaf(hsLs[f], cw[f * 32 + t], cv);
        float s = cv, q = cv * cv;
#pragma unroll
        for (int m = 1; m <= 16; m <<= 1) { s += __shfl_xor(s, m); q += __shfl_xor(q, m); }
        const float mu = s * (1.f / 32.f);
        const float rsg = rsqrtf(fmaf(q, 1.f / 32.f, -mu * mu) + 1e-5f);
        const float v = fmaf(fmaf(cv, rsg, -mu * rsg), clnw[t], clnb[t]);
        combL[t] = has ? fmaxf(v, 0.f) : 0.f;
    }
    __syncthreads();

    float h0 = eb1[t], h1v = eb1[t + 128];
#pragma unroll 4
    for (int d = 0; d < 32; ++d) {
        const float cd = combL[d];
        h0  = fmaf(cd, ew1[d * 256 + t], h0);
        h1v = fmaf(cd, ew1[d * 256 + t + 128], h1v);
    }
    {
        float s = h0 + h1v, q = h0 * h0 + h1v * h1v;
#pragma unroll
        for (int m = 1; m <= 32; m <<= 1) { s += __shfl_xor(s, m); q += __shfl_xor(q, m); }
        const int wv = t >> 6, ln = t & 63;
        if (ln == 0) { red[wv * 2] = s; red[wv * 2 + 1] = q; }
    }
    __syncthreads();
    {
        const float S = red[0] + red[2], Q = red[1] + red[3];
        const float mu1 = S * (1.f / 256.f);
        const float rs1 = rsqrtf(fmaf(Q, 1.f / 256.f, -mu1 * mu1) + 1e-5f);
        hL[t]       = fmaxf(fmaf(fmaf(h0,  rs1, -mu1 * rs1), l1w[t],       l1b[t]),       0.f);
        hL[t + 128] = fmaxf(fmaf(fmaf(h1v, rs1, -mu1 * rs1), l1w[t + 128], l1b[t + 128]), 0.f);
    }
    __syncthreads();

    if (t < 64) {
        float ov = eb2[t];
#pragma unroll 4
        for (int m = 0; m < 256; ++m) ov = fmaf(hL[m], ew2[m * 64 + t], ov);
        float s = ov, q = ov * ov;
#pragma unroll
        for (int m = 1; m <= 32; m <<= 1) { s += __shfl_xor(s, m); q += __shfl_xor(q, m); }
        const float mu2 = s * (1.f / 64.f);
        const float rs2 = rsqrtf(fmaf(q, 1.f / 64.f, -mu2 * mu2) + 1e-5f);
        const float o = fmaxf(fmaf(fmaf(ov, rs2, -mu2 * rs2), l2w[t], l2b[t]), 0.f);
        if (t < 32) out[b * 32 + t] = o;
        else        out[4096 + b * 32 + (t - 32)] = o;
    }
}

// ---------------------------------------------------------------------------
extern "C" void kernel_launch(void* const* d_in, const int* in_sizes, int n_in,
                              void* d_out, int out_size, void* d_ws, size_t ws_size,
                              hipStream_t stream)
{
    (void)in_sizes; (void)n_in; (void)out_size; (void)ws_size;
    const float* x    = (const float*)d_in[0];
    const int*   mask = (const int*)d_in[1];
    const float* fe   = (const float*)d_in[2];
    const float* hw1  = (const float*)d_in[3];
    const float* hb1  = (const float*)d_in[4];
    const float* ln1w = (const float*)d_in[5];
    const float* ln1b = (const float*)d_in[6];
    const float* hw2  = (const float*)d_in[7];
    const float* hb2  = (const float*)d_in[8];
    const float* ln2w = (const float*)d_in[9];
    const float* ln2b = (const float*)d_in[10];
    const float* gw1  = (const float*)d_in[11];
    const float* gb1  = (const float*)d_in[12];
    const float* gw2  = (const float*)d_in[13];
    const float* gb2  = (const float*)d_in[14];
    const float* cw   = (const float*)d_in[15];
    const float* cbv  = (const float*)d_in[16];
    const float* clnw = (const float*)d_in[17];
    const float* clnb = (const float*)d_in[18];
    const float* ew1  = (const float*)d_in[19];
    const float* eb1  = (const float*)d_in[20];
    const float* l1w  = (const float*)d_in[21];
    const float* l1b  = (const float*)d_in[22];
    const float* ew2  = (const float*)d_in[23];
    const float* eb2  = (const float*)d_in[24];
    const float* l2w  = (const float*)d_in[25];
    const float* l2b  = (const float*)d_in[26];

    const size_t fragOff = (2u << 20) + (128u << 10) + 256u;          // feWb + aux + scal
    const size_t pOff    = fragOff + 9u * 64u * 16u;                  // + 9KB fragments
    const size_t seOff   = pOff + (size_t)32 * 32 * 512 * 4;          // + 2MB P

    char* ws = (char*)d_ws;
    unsigned short* feWb = (unsigned short*)ws;                       // 2 MB
    float* aux   = (float*)(ws + (2u << 20));                         // 128 KB
    float* scal  = (float*)(ws + (2u << 20) + (128u << 10));          // 256 B
    uint4* fragW = (uint4*)(ws + fragOff);                            // 9 KB
    float* P     = (float*)(ws + pOff);                               // 2 MB
    float* SEb   = (float*)(ws + seOff);                              // 64 KB

    hipLaunchKernelGGL(k_prep, dim3(JDIM / 8), dim3(128), 0, stream,
                       fe, hw1, hb1, hw2, gw1, feWb, aux, scal, fragW);
    hipLaunchKernelGGL(k_main, dim3(32, 32), dim3(256), 0, stream,
                       x, mask, feWb, aux, scal, fragW,
                       hw1, ln1w, ln1b, hb2, ln2w, ln2b,
                       gb1, gw2, gb2, P, SEb);
    hipLaunchKernelGGL(k_tail, dim3(BDIM), dim3(128), 0, stream,
                       P, SEb, cw, cbv, clnw, clnb,
                       ew1, eb1, l1w, l1b, ew2, eb2, l2w, l2b,
                       (float*)d_out);
}